// Round 1
// baseline (489.637 us; speedup 1.0000x reference)
//
#include <hip/hip_runtime.h>

#define N_NODES  10000
#define N_EDGES  320000
#define D        256
#define N_TASKS  128
#define N_GRAPHS 128

// ---------------- CSR build ----------------

__global__ void init_kernel(int* __restrict__ cnt, int* __restrict__ fill) {
    int i = blockIdx.x * blockDim.x + threadIdx.x;
    if (i < N_NODES) { cnt[i] = 1; fill[i] = 0; }   // cnt starts at 1: self-loop
}

__global__ void hist_kernel(const int* __restrict__ dst, int* __restrict__ cnt) {
    int e = blockIdx.x * blockDim.x + threadIdx.x;
    if (e < N_EDGES) atomicAdd(&cnt[dst[e]], 1);
}

// One block, 256 threads. Exclusive scan of (cnt[i]-1) -> rowptr (real in-edges
// only; self-loop handled analytically in agg). Also emits isd = rsqrt(deg).
__global__ void scan_kernel(const int* __restrict__ cnt, int* __restrict__ rowptr,
                            float* __restrict__ isd) {
    __shared__ int part[256];
    const int CH = 40;  // 256*40 = 10240 >= N_NODES
    int t = threadIdx.x;
    int base = t * CH;
    int s = 0;
    for (int i = 0; i < CH; ++i) {
        int idx = base + i;
        if (idx < N_NODES) s += cnt[idx] - 1;
    }
    part[t] = s;
    __syncthreads();
    for (int off = 1; off < 256; off <<= 1) {
        int v = (t >= off) ? part[t - off] : 0;
        __syncthreads();
        part[t] += v;
        __syncthreads();
    }
    int run = (t == 0) ? 0 : part[t - 1];
    for (int i = 0; i < CH; ++i) {
        int idx = base + i;
        if (idx < N_NODES) {
            rowptr[idx] = run;
            run += cnt[idx] - 1;
            isd[idx] = rsqrtf((float)cnt[idx]);
        }
    }
    if (t == 255) rowptr[N_NODES] = run;  // == N_EDGES
}

__global__ void fillcsr_kernel(const int* __restrict__ src, const int* __restrict__ dst,
                               const int* __restrict__ rowptr, int* __restrict__ fill,
                               int* __restrict__ slot) {
    int e = blockIdx.x * blockDim.x + threadIdx.x;
    if (e < N_EDGES) {
        int d = dst[e];
        int pos = rowptr[d] + atomicAdd(&fill[d], 1);
        slot[pos] = src[e];
    }
}

// ---------------- dense matmul: C[N,256] = A[N,256] @ W[256,256] ----------------
// 32 rows per block, 256 threads; thread owns one output column.
__global__ __launch_bounds__(256) void matmul_kernel(const float* __restrict__ A,
                                                     const float* __restrict__ W,
                                                     float* __restrict__ C) {
    __shared__ float xs[32][D];  // 32 KiB
    int row0 = blockIdx.x * 32;
    int tid = threadIdx.x;
    for (int r = 0; r < 32; ++r) {
        int row = row0 + r;
        xs[r][tid] = (row < N_NODES) ? A[row * D + tid] : 0.f;
    }
    __syncthreads();
    float acc[32];
#pragma unroll
    for (int r = 0; r < 32; ++r) acc[r] = 0.f;
    for (int k = 0; k < D; k += 4) {
        float w0 = W[(k + 0) * D + tid];
        float w1 = W[(k + 1) * D + tid];
        float w2 = W[(k + 2) * D + tid];
        float w3 = W[(k + 3) * D + tid];
#pragma unroll
        for (int r = 0; r < 32; ++r) {
            float4 xv = *reinterpret_cast<const float4*>(&xs[r][k]);
            acc[r] = fmaf(xv.x, w0, acc[r]);
            acc[r] = fmaf(xv.y, w1, acc[r]);
            acc[r] = fmaf(xv.z, w2, acc[r]);
            acc[r] = fmaf(xv.w, w3, acc[r]);
        }
    }
    for (int r = 0; r < 32; ++r) {
        int row = row0 + r;
        if (row < N_NODES) C[row * D + tid] = acc[r];
    }
}

// ---------------- aggregation: out[i] = relu(b + sum_{e: dst=i} h[src]*norm) --------
// One wave per node; lane holds 4 dims via float4 (64*4 = 256).
__global__ __launch_bounds__(256) void agg_kernel(const float* __restrict__ h,
                                                  const int* __restrict__ rowptr,
                                                  const int* __restrict__ slot,
                                                  const float* __restrict__ isd,
                                                  const float* __restrict__ bias,
                                                  float* __restrict__ out) {
    int wave = (blockIdx.x * blockDim.x + threadIdx.x) >> 6;
    int lane = threadIdx.x & 63;
    if (wave >= N_NODES) return;
    int node = wave;
    float isd_i = isd[node];
    float selfn = isd_i * isd_i;  // self-loop norm = 1/deg
    float4 a = reinterpret_cast<const float4*>(h + (size_t)node * D)[lane];
    float4 acc;
    acc.x = a.x * selfn; acc.y = a.y * selfn; acc.z = a.z * selfn; acc.w = a.w * selfn;
    int e0 = rowptr[node], e1 = rowptr[node + 1];
    for (int e = e0; e < e1; ++e) {
        int s = slot[e];
        float nrm = isd[s] * isd_i;
        float4 v = reinterpret_cast<const float4*>(h + (size_t)s * D)[lane];
        acc.x = fmaf(v.x, nrm, acc.x);
        acc.y = fmaf(v.y, nrm, acc.y);
        acc.z = fmaf(v.z, nrm, acc.z);
        acc.w = fmaf(v.w, nrm, acc.w);
    }
    float4 b4 = reinterpret_cast<const float4*>(bias)[lane];
    acc.x = fmaxf(acc.x + b4.x, 0.f);
    acc.y = fmaxf(acc.y + b4.y, 0.f);
    acc.z = fmaxf(acc.z + b4.z, 0.f);
    acc.w = fmaxf(acc.w + b4.w, 0.f);
    reinterpret_cast<float4*>(out + (size_t)node * D)[lane] = acc;
}

// ---------------- mean-pool over sorted batch ids ----------------
__global__ void pool_kernel(const float* __restrict__ h, const int* __restrict__ batch,
                            float* __restrict__ pooled) {
    int g = blockIdx.x;
    int tid = threadIdx.x;  // 256 threads = 256 dims
    int lo = 0, hi = N_NODES;
    while (lo < hi) { int mid = (lo + hi) >> 1; if (batch[mid] < g) lo = mid + 1; else hi = mid; }
    int start = lo;
    hi = N_NODES;
    while (lo < hi) { int mid = (lo + hi) >> 1; if (batch[mid] < g + 1) lo = mid + 1; else hi = mid; }
    int end = lo;
    float acc = 0.f;
    for (int nd = start; nd < end; ++nd) acc += h[(size_t)nd * D + tid];
    float c = (end > start) ? (float)(end - start) : 1.f;
    pooled[g * D + tid] = acc / c;
}

// ---------------- head: out[G,128] = pooled @ lin_w + lin_b ----------------
__global__ void final_kernel(const float* __restrict__ pooled, const float* __restrict__ lw,
                             const float* __restrict__ lb, float* __restrict__ out) {
    int g = blockIdx.x;
    int j = threadIdx.x;  // 128 threads
    __shared__ float p[D];
    p[j] = pooled[g * D + j];
    p[j + 128] = pooled[g * D + j + 128];
    __syncthreads();
    float acc = lb[j];
    for (int k = 0; k < D; ++k) acc = fmaf(p[k], lw[k * N_TASKS + j], acc);
    out[g * N_TASKS + j] = acc;
}

extern "C" void kernel_launch(void* const* d_in, const int* in_sizes, int n_in,
                              void* d_out, int out_size, void* d_ws, size_t ws_size,
                              hipStream_t stream) {
    const float* x   = (const float*)d_in[0];
    const int*   ei  = (const int*)d_in[1];
    const int*   bat = (const int*)d_in[2];
    const float* W1  = (const float*)d_in[3];
    const float* b1  = (const float*)d_in[4];
    const float* W2  = (const float*)d_in[5];
    const float* b2  = (const float*)d_in[6];
    const float* W3  = (const float*)d_in[7];
    const float* b3  = (const float*)d_in[8];
    const float* lw  = (const float*)d_in[9];
    const float* lb  = (const float*)d_in[10];
    float* out = (float*)d_out;

    const int* src = ei;
    const int* dst = ei + N_EDGES;

    char* ws = (char*)d_ws;
    float* hA     = (float*)(ws + 0);                 // 10,240,000 B
    float* hB     = (float*)(ws + 10240000);          // 10,240,000 B
    float* pooled = (float*)(ws + 20480000);          //    131,072 B
    float* isd    = (float*)(ws + 20611072);          //     40,000 B
    int*   cnt    = (int*)  (ws + 20651072);          //     40,000 B
    int*   fill   = (int*)  (ws + 20691072);          //     40,000 B
    int*   rowptr = (int*)  (ws + 20731072);          //     40,016 B
    int*   slot   = (int*)  (ws + 20771088);          //  1,280,000 B  (total ~22.05 MB)

    // CSR build (once per call)
    init_kernel<<<(N_NODES + 255) / 256, 256, 0, stream>>>(cnt, fill);
    hist_kernel<<<(N_EDGES + 255) / 256, 256, 0, stream>>>(dst, cnt);
    scan_kernel<<<1, 256, 0, stream>>>(cnt, rowptr, isd);
    fillcsr_kernel<<<(N_EDGES + 255) / 256, 256, 0, stream>>>(src, dst, rowptr, fill, slot);

    const int MM_BLOCKS = (N_NODES + 31) / 32;  // 313
    const int AGG_BLOCKS = N_NODES / 4;         // 2500 (4 waves/block, 1 node/wave)

    // Layer 1
    matmul_kernel<<<MM_BLOCKS, 256, 0, stream>>>(x, W1, hB);
    agg_kernel<<<AGG_BLOCKS, 256, 0, stream>>>(hB, rowptr, slot, isd, b1, hA);
    // Layer 2
    matmul_kernel<<<MM_BLOCKS, 256, 0, stream>>>(hA, W2, hB);
    agg_kernel<<<AGG_BLOCKS, 256, 0, stream>>>(hB, rowptr, slot, isd, b2, hA);
    // Layer 3
    matmul_kernel<<<MM_BLOCKS, 256, 0, stream>>>(hA, W3, hB);
    agg_kernel<<<AGG_BLOCKS, 256, 0, stream>>>(hB, rowptr, slot, isd, b3, hA);

    // Pool + head
    pool_kernel<<<N_GRAPHS, 256, 0, stream>>>(hA, bat, pooled);
    final_kernel<<<N_GRAPHS, 128, 0, stream>>>(pooled, lw, lb, out);
}

// Round 2
// 346.255 us; speedup vs baseline: 1.4141x; 1.4141x over previous
//
#include <hip/hip_runtime.h>

#define N_NODES  10000
#define N_EDGES  320000
#define D        256
#define N_TASKS  128
#define N_GRAPHS 128

// ---------------- CSR build ----------------

__global__ void init_kernel(int* __restrict__ cnt, int* __restrict__ fill) {
    int i = blockIdx.x * blockDim.x + threadIdx.x;
    if (i < N_NODES) { cnt[i] = 1; fill[i] = 0; }   // cnt starts at 1: self-loop
}

__global__ void hist_kernel(const int* __restrict__ dst, int* __restrict__ cnt) {
    int e = blockIdx.x * blockDim.x + threadIdx.x;
    if (e < N_EDGES) atomicAdd(&cnt[dst[e]], 1);
}

// One block, 256 threads. Exclusive scan of (cnt[i]-1) -> rowptr (real in-edges
// only; self-loop handled analytically in agg). Also emits isd = rsqrt(deg).
__global__ void scan_kernel(const int* __restrict__ cnt, int* __restrict__ rowptr,
                            float* __restrict__ isd) {
    __shared__ int part[256];
    const int CH = 40;  // 256*40 = 10240 >= N_NODES
    int t = threadIdx.x;
    int base = t * CH;
    int s = 0;
    for (int i = 0; i < CH; ++i) {
        int idx = base + i;
        if (idx < N_NODES) s += cnt[idx] - 1;
    }
    part[t] = s;
    __syncthreads();
    for (int off = 1; off < 256; off <<= 1) {
        int v = (t >= off) ? part[t - off] : 0;
        __syncthreads();
        part[t] += v;
        __syncthreads();
    }
    int run = (t == 0) ? 0 : part[t - 1];
    for (int i = 0; i < CH; ++i) {
        int idx = base + i;
        if (idx < N_NODES) {
            rowptr[idx] = run;
            run += cnt[idx] - 1;
            isd[idx] = rsqrtf((float)cnt[idx]);
        }
    }
    if (t == 255) rowptr[N_NODES] = run;  // == N_EDGES
}

__global__ void fillcsr_kernel(const int* __restrict__ src, const int* __restrict__ dst,
                               const int* __restrict__ rowptr, int* __restrict__ fill,
                               int* __restrict__ slot) {
    int e = blockIdx.x * blockDim.x + threadIdx.x;
    if (e < N_EDGES) {
        int d = dst[e];
        int pos = rowptr[d] + atomicAdd(&fill[d], 1);
        slot[pos] = src[e];
    }
}

// ---------------- dense matmul: C[N,256] = A[N,256] @ W[256,256] ----------------
// Register-tiled: BM=64 x BN=64 tile per block, BK=16, 256 threads, 4x4 per
// thread. A-tile stored k-major ([BK][BM+4]) so the 4-row fragment is one
// ds_read_b128 (4 distinct addrs/wave, 16-lane broadcast -> conflict-free).
// Grid 157x4 = 628 blocks (~2.5 blocks/CU -> ~10 waves/CU).
#define BM 64
#define BN 64
#define BK 16

__global__ __launch_bounds__(256) void matmul_kernel(const float* __restrict__ A,
                                                     const float* __restrict__ W,
                                                     float* __restrict__ C) {
    __shared__ float As[BK][BM + 4];  // pad->68 floats/row: write 2-way (free), read conflict-free
    __shared__ float Ws[BK][BN + 4];

    int tid = threadIdx.x;
    int row0 = blockIdx.x * BM;
    int n0 = blockIdx.y * BN;
    int tm = tid >> 4;   // 0..15 -> rows tm*4..+3
    int tn = tid & 15;   // 0..15 -> cols tn*4..+3

    // global->reg load indices
    int lr = tid >> 2;          // 0..63 A-tile row
    int lk = (tid & 3) << 2;    // 0,4,8,12 k offset
    int wk = tid >> 4;          // 0..15 W-tile k row
    int wn = (tid & 15) << 2;   // 0..60 col offset
    int arow = row0 + lr; if (arow >= N_NODES) arow = N_NODES - 1;  // clamp (stores guarded)
    const float* aptr = A + (size_t)arow * D + lk;
    const float* wptr = W + (size_t)wk * D + n0 + wn;

    float4 areg = *reinterpret_cast<const float4*>(aptr);
    float4 wreg = *reinterpret_cast<const float4*>(wptr);

    float acc[4][4];
#pragma unroll
    for (int i = 0; i < 4; ++i)
#pragma unroll
        for (int j = 0; j < 4; ++j) acc[i][j] = 0.f;

#pragma unroll 1
    for (int step = 0; step < D / BK; ++step) {
        // regs -> LDS (A transposed to k-major)
        As[lk + 0][lr] = areg.x;
        As[lk + 1][lr] = areg.y;
        As[lk + 2][lr] = areg.z;
        As[lk + 3][lr] = areg.w;
        *reinterpret_cast<float4*>(&Ws[wk][wn]) = wreg;
        __syncthreads();
        if (step < D / BK - 1) {  // prefetch next tile (overlaps with compute below)
            areg = *reinterpret_cast<const float4*>(aptr + (step + 1) * BK);
            wreg = *reinterpret_cast<const float4*>(wptr + (size_t)(step + 1) * BK * D);
        }
#pragma unroll
        for (int kk = 0; kk < BK; ++kk) {
            float4 a4 = *reinterpret_cast<const float4*>(&As[kk][tm << 2]);
            float4 b4 = *reinterpret_cast<const float4*>(&Ws[kk][tn << 2]);
            acc[0][0] = fmaf(a4.x, b4.x, acc[0][0]);
            acc[0][1] = fmaf(a4.x, b4.y, acc[0][1]);
            acc[0][2] = fmaf(a4.x, b4.z, acc[0][2]);
            acc[0][3] = fmaf(a4.x, b4.w, acc[0][3]);
            acc[1][0] = fmaf(a4.y, b4.x, acc[1][0]);
            acc[1][1] = fmaf(a4.y, b4.y, acc[1][1]);
            acc[1][2] = fmaf(a4.y, b4.z, acc[1][2]);
            acc[1][3] = fmaf(a4.y, b4.w, acc[1][3]);
            acc[2][0] = fmaf(a4.z, b4.x, acc[2][0]);
            acc[2][1] = fmaf(a4.z, b4.y, acc[2][1]);
            acc[2][2] = fmaf(a4.z, b4.z, acc[2][2]);
            acc[2][3] = fmaf(a4.z, b4.w, acc[2][3]);
            acc[3][0] = fmaf(a4.w, b4.x, acc[3][0]);
            acc[3][1] = fmaf(a4.w, b4.y, acc[3][1]);
            acc[3][2] = fmaf(a4.w, b4.z, acc[3][2]);
            acc[3][3] = fmaf(a4.w, b4.w, acc[3][3]);
        }
        __syncthreads();
    }

#pragma unroll
    for (int i = 0; i < 4; ++i) {
        int row = row0 + (tm << 2) + i;
        if (row < N_NODES) {
            float4 v = make_float4(acc[i][0], acc[i][1], acc[i][2], acc[i][3]);
            *reinterpret_cast<float4*>(C + (size_t)row * D + n0 + (tn << 2)) = v;
        }
    }
}

// ---------------- aggregation: out[i] = relu(b + sum_{e: dst=i} h[src]*norm) --------
// One wave per node; lane holds 4 dims via float4 (64*4 = 256).
__global__ __launch_bounds__(256) void agg_kernel(const float* __restrict__ h,
                                                  const int* __restrict__ rowptr,
                                                  const int* __restrict__ slot,
                                                  const float* __restrict__ isd,
                                                  const float* __restrict__ bias,
                                                  float* __restrict__ out) {
    int wave = (blockIdx.x * blockDim.x + threadIdx.x) >> 6;
    int lane = threadIdx.x & 63;
    if (wave >= N_NODES) return;
    int node = wave;
    float isd_i = isd[node];
    float selfn = isd_i * isd_i;  // self-loop norm = 1/deg
    float4 a = reinterpret_cast<const float4*>(h + (size_t)node * D)[lane];
    float4 acc;
    acc.x = a.x * selfn; acc.y = a.y * selfn; acc.z = a.z * selfn; acc.w = a.w * selfn;
    int e0 = rowptr[node], e1 = rowptr[node + 1];
    for (int e = e0; e < e1; ++e) {
        int s = slot[e];
        float nrm = isd[s] * isd_i;
        float4 v = reinterpret_cast<const float4*>(h + (size_t)s * D)[lane];
        acc.x = fmaf(v.x, nrm, acc.x);
        acc.y = fmaf(v.y, nrm, acc.y);
        acc.z = fmaf(v.z, nrm, acc.z);
        acc.w = fmaf(v.w, nrm, acc.w);
    }
    float4 b4 = reinterpret_cast<const float4*>(bias)[lane];
    acc.x = fmaxf(acc.x + b4.x, 0.f);
    acc.y = fmaxf(acc.y + b4.y, 0.f);
    acc.z = fmaxf(acc.z + b4.z, 0.f);
    acc.w = fmaxf(acc.w + b4.w, 0.f);
    reinterpret_cast<float4*>(out + (size_t)node * D)[lane] = acc;
}

// ---------------- mean-pool over sorted batch ids ----------------
__global__ void pool_kernel(const float* __restrict__ h, const int* __restrict__ batch,
                            float* __restrict__ pooled) {
    int g = blockIdx.x;
    int tid = threadIdx.x;  // 256 threads = 256 dims
    int lo = 0, hi = N_NODES;
    while (lo < hi) { int mid = (lo + hi) >> 1; if (batch[mid] < g) lo = mid + 1; else hi = mid; }
    int start = lo;
    hi = N_NODES;
    while (lo < hi) { int mid = (lo + hi) >> 1; if (batch[mid] < g + 1) lo = mid + 1; else hi = mid; }
    int end = lo;
    float acc = 0.f;
    for (int nd = start; nd < end; ++nd) acc += h[(size_t)nd * D + tid];
    float c = (end > start) ? (float)(end - start) : 1.f;
    pooled[g * D + tid] = acc / c;
}

// ---------------- head: out[G,128] = pooled @ lin_w + lin_b ----------------
__global__ void final_kernel(const float* __restrict__ pooled, const float* __restrict__ lw,
                             const float* __restrict__ lb, float* __restrict__ out) {
    int g = blockIdx.x;
    int j = threadIdx.x;  // 128 threads
    __shared__ float p[D];
    p[j] = pooled[g * D + j];
    p[j + 128] = pooled[g * D + j + 128];
    __syncthreads();
    float acc = lb[j];
    for (int k = 0; k < D; ++k) acc = fmaf(p[k], lw[k * N_TASKS + j], acc);
    out[g * N_TASKS + j] = acc;
}

extern "C" void kernel_launch(void* const* d_in, const int* in_sizes, int n_in,
                              void* d_out, int out_size, void* d_ws, size_t ws_size,
                              hipStream_t stream) {
    const float* x   = (const float*)d_in[0];
    const int*   ei  = (const int*)d_in[1];
    const int*   bat = (const int*)d_in[2];
    const float* W1  = (const float*)d_in[3];
    const float* b1  = (const float*)d_in[4];
    const float* W2  = (const float*)d_in[5];
    const float* b2  = (const float*)d_in[6];
    const float* W3  = (const float*)d_in[7];
    const float* b3  = (const float*)d_in[8];
    const float* lw  = (const float*)d_in[9];
    const float* lb  = (const float*)d_in[10];
    float* out = (float*)d_out;

    const int* src = ei;
    const int* dst = ei + N_EDGES;

    char* ws = (char*)d_ws;
    float* hA     = (float*)(ws + 0);                 // 10,240,000 B
    float* hB     = (float*)(ws + 10240000);          // 10,240,000 B
    float* pooled = (float*)(ws + 20480000);          //    131,072 B
    float* isd    = (float*)(ws + 20611072);          //     40,000 B
    int*   cnt    = (int*)  (ws + 20651072);          //     40,000 B
    int*   fill   = (int*)  (ws + 20691072);          //     40,000 B
    int*   rowptr = (int*)  (ws + 20731072);          //     40,016 B
    int*   slot   = (int*)  (ws + 20771088);          //  1,280,000 B  (total ~22.05 MB)

    // CSR build (once per call)
    init_kernel<<<(N_NODES + 255) / 256, 256, 0, stream>>>(cnt, fill);
    hist_kernel<<<(N_EDGES + 255) / 256, 256, 0, stream>>>(dst, cnt);
    scan_kernel<<<1, 256, 0, stream>>>(cnt, rowptr, isd);
    fillcsr_kernel<<<(N_EDGES + 255) / 256, 256, 0, stream>>>(src, dst, rowptr, fill, slot);

    dim3 mmgrid((N_NODES + BM - 1) / BM, D / BN);   // 157 x 4 = 628 blocks
    const int AGG_BLOCKS = N_NODES / 4;             // 2500 (4 waves/block, 1 node/wave)

    // Layer 1
    matmul_kernel<<<mmgrid, 256, 0, stream>>>(x, W1, hB);
    agg_kernel<<<AGG_BLOCKS, 256, 0, stream>>>(hB, rowptr, slot, isd, b1, hA);
    // Layer 2
    matmul_kernel<<<mmgrid, 256, 0, stream>>>(hA, W2, hB);
    agg_kernel<<<AGG_BLOCKS, 256, 0, stream>>>(hB, rowptr, slot, isd, b2, hA);
    // Layer 3
    matmul_kernel<<<mmgrid, 256, 0, stream>>>(hA, W3, hB);
    agg_kernel<<<AGG_BLOCKS, 256, 0, stream>>>(hB, rowptr, slot, isd, b3, hA);

    // Pool + head
    pool_kernel<<<N_GRAPHS, 256, 0, stream>>>(hA, bat, pooled);
    final_kernel<<<N_GRAPHS, 128, 0, stream>>>(pooled, lw, lb, out);
}

// Round 3
// 301.695 us; speedup vs baseline: 1.6230x; 1.1477x over previous
//
#include <hip/hip_runtime.h>

#define N_NODES  10000
#define N_EDGES  320000
#define D        256
#define N_TASKS  128
#define N_GRAPHS 128

// ---------------- CSR build ----------------

__global__ void init_kernel(int* __restrict__ cnt, int* __restrict__ fill,
                            float* __restrict__ pooled) {
    int i = blockIdx.x * blockDim.x + threadIdx.x;
    if (i < N_NODES) { cnt[i] = 1; fill[i] = 0; }   // cnt starts at 1: self-loop
    if (i < N_GRAPHS * D) pooled[i] = 0.f;          // zero pool accumulators
}

__global__ void hist_kernel(const int* __restrict__ dst, int* __restrict__ cnt) {
    int e = blockIdx.x * blockDim.x + threadIdx.x;
    if (e < N_EDGES) atomicAdd(&cnt[dst[e]], 1);
}

// One block, 256 threads. cnt staged in LDS (coalesced), then exclusive scan of
// (cnt-1) -> rowptr (in-edges only; self-loop handled analytically in agg).
__global__ __launch_bounds__(256) void scan_kernel(const int* __restrict__ cnt,
                                                   int* __restrict__ rowptr,
                                                   float* __restrict__ isd) {
    __shared__ int scnt[10240];
    __shared__ int part[256];
    const int CH = 40;  // 256*40 = 10240 >= N_NODES
    int t = threadIdx.x;
    for (int i = t; i < 10240; i += 256) scnt[i] = (i < N_NODES) ? cnt[i] : 1;
    __syncthreads();
    int base = t * CH;
    int s = 0;
#pragma unroll 8
    for (int i = 0; i < CH; ++i) s += scnt[base + i] - 1;
    part[t] = s;
    __syncthreads();
    for (int off = 1; off < 256; off <<= 1) {
        int v = (t >= off) ? part[t - off] : 0;
        __syncthreads();
        part[t] += v;
        __syncthreads();
    }
    int run = (t == 0) ? 0 : part[t - 1];
    for (int i = 0; i < CH; ++i) {
        int idx = base + i;
        if (idx < N_NODES) {
            rowptr[idx] = run;
            int c = scnt[idx];
            run += c - 1;
            isd[idx] = rsqrtf((float)c);
        }
    }
    if (t == 255) rowptr[N_NODES] = run;  // == N_EDGES
}

// Emit per-edge {src, isd[src]*isd[dst]} so agg's inner loop has no dependent
// random isd gather (and the product is computed once, reused by 3 layers).
__global__ void fillcsr_kernel(const int* __restrict__ src, const int* __restrict__ dst,
                               const int* __restrict__ rowptr, const float* __restrict__ isd,
                               int* __restrict__ fill, int2* __restrict__ edat) {
    int e = blockIdx.x * blockDim.x + threadIdx.x;
    if (e < N_EDGES) {
        int s = src[e], d = dst[e];
        int pos = rowptr[d] + atomicAdd(&fill[d], 1);
        edat[pos] = make_int2(s, __float_as_int(isd[s] * isd[d]));
    }
}

// ---------------- dense matmul: C[N,256] = A[N,256] @ W[256,256] ----------------
#define BM 64
#define BN 64
#define BK 16

__global__ __launch_bounds__(256) void matmul_kernel(const float* __restrict__ A,
                                                     const float* __restrict__ W,
                                                     float* __restrict__ C) {
    __shared__ float As[BK][BM + 4];
    __shared__ float Ws[BK][BN + 4];

    int tid = threadIdx.x;
    int row0 = blockIdx.x * BM;
    int n0 = blockIdx.y * BN;
    int tm = tid >> 4;
    int tn = tid & 15;

    int lr = tid >> 2;
    int lk = (tid & 3) << 2;
    int wk = tid >> 4;
    int wn = (tid & 15) << 2;
    int arow = row0 + lr; if (arow >= N_NODES) arow = N_NODES - 1;
    const float* aptr = A + (size_t)arow * D + lk;
    const float* wptr = W + (size_t)wk * D + n0 + wn;

    float4 areg = *reinterpret_cast<const float4*>(aptr);
    float4 wreg = *reinterpret_cast<const float4*>(wptr);

    float acc[4][4];
#pragma unroll
    for (int i = 0; i < 4; ++i)
#pragma unroll
        for (int j = 0; j < 4; ++j) acc[i][j] = 0.f;

#pragma unroll 1
    for (int step = 0; step < D / BK; ++step) {
        As[lk + 0][lr] = areg.x;
        As[lk + 1][lr] = areg.y;
        As[lk + 2][lr] = areg.z;
        As[lk + 3][lr] = areg.w;
        *reinterpret_cast<float4*>(&Ws[wk][wn]) = wreg;
        __syncthreads();
        if (step < D / BK - 1) {
            areg = *reinterpret_cast<const float4*>(aptr + (step + 1) * BK);
            wreg = *reinterpret_cast<const float4*>(wptr + (size_t)(step + 1) * BK * D);
        }
#pragma unroll
        for (int kk = 0; kk < BK; ++kk) {
            float4 a4 = *reinterpret_cast<const float4*>(&As[kk][tm << 2]);
            float4 b4 = *reinterpret_cast<const float4*>(&Ws[kk][tn << 2]);
            acc[0][0] = fmaf(a4.x, b4.x, acc[0][0]);
            acc[0][1] = fmaf(a4.x, b4.y, acc[0][1]);
            acc[0][2] = fmaf(a4.x, b4.z, acc[0][2]);
            acc[0][3] = fmaf(a4.x, b4.w, acc[0][3]);
            acc[1][0] = fmaf(a4.y, b4.x, acc[1][0]);
            acc[1][1] = fmaf(a4.y, b4.y, acc[1][1]);
            acc[1][2] = fmaf(a4.y, b4.z, acc[1][2]);
            acc[1][3] = fmaf(a4.y, b4.w, acc[1][3]);
            acc[2][0] = fmaf(a4.z, b4.x, acc[2][0]);
            acc[2][1] = fmaf(a4.z, b4.y, acc[2][1]);
            acc[2][2] = fmaf(a4.z, b4.z, acc[2][2]);
            acc[2][3] = fmaf(a4.z, b4.w, acc[2][3]);
            acc[3][0] = fmaf(a4.w, b4.x, acc[3][0]);
            acc[3][1] = fmaf(a4.w, b4.y, acc[3][1]);
            acc[3][2] = fmaf(a4.w, b4.z, acc[3][2]);
            acc[3][3] = fmaf(a4.w, b4.w, acc[3][3]);
        }
        __syncthreads();
    }

#pragma unroll
    for (int i = 0; i < 4; ++i) {
        int row = row0 + (tm << 2) + i;
        if (row < N_NODES) {
            float4 v = make_float4(acc[i][0], acc[i][1], acc[i][2], acc[i][3]);
            *reinterpret_cast<float4*>(C + (size_t)row * D + n0 + (tn << 2)) = v;
        }
    }
}

// ---------------- aggregation: out[i] = relu(b + sum_{e: dst=i} h[src]*w) --------
// One wave per node; lane holds 4 dims (float4). Edge loop unrolled x8 so 8
// 1KB row-gathers are in flight per wave (latency hiding); edge weight is
// precomputed in edat (no dependent isd gather on the critical chain).
__global__ __launch_bounds__(256) void agg_kernel(const float* __restrict__ h,
                                                  const int* __restrict__ rowptr,
                                                  const int2* __restrict__ edat,
                                                  const float* __restrict__ isd,
                                                  const float* __restrict__ bias,
                                                  float* __restrict__ out) {
    int wave = (blockIdx.x * blockDim.x + threadIdx.x) >> 6;
    int lane = threadIdx.x & 63;
    if (wave >= N_NODES) return;
    int node = wave;
    float isd_i = isd[node];
    float selfn = isd_i * isd_i;  // self-loop norm = 1/deg
    float4 a = reinterpret_cast<const float4*>(h + (size_t)node * D)[lane];
    float4 acc = make_float4(a.x * selfn, a.y * selfn, a.z * selfn, a.w * selfn);
    int e0 = rowptr[node], e1 = rowptr[node + 1];
    int e = e0;
    for (; e + 8 <= e1; e += 8) {
        int2 d0 = edat[e + 0]; int2 d1 = edat[e + 1];
        int2 d2 = edat[e + 2]; int2 d3 = edat[e + 3];
        int2 d4 = edat[e + 4]; int2 d5 = edat[e + 5];
        int2 d6 = edat[e + 6]; int2 d7 = edat[e + 7];
        float4 v0 = reinterpret_cast<const float4*>(h + (size_t)d0.x * D)[lane];
        float4 v1 = reinterpret_cast<const float4*>(h + (size_t)d1.x * D)[lane];
        float4 v2 = reinterpret_cast<const float4*>(h + (size_t)d2.x * D)[lane];
        float4 v3 = reinterpret_cast<const float4*>(h + (size_t)d3.x * D)[lane];
        float4 v4 = reinterpret_cast<const float4*>(h + (size_t)d4.x * D)[lane];
        float4 v5 = reinterpret_cast<const float4*>(h + (size_t)d5.x * D)[lane];
        float4 v6 = reinterpret_cast<const float4*>(h + (size_t)d6.x * D)[lane];
        float4 v7 = reinterpret_cast<const float4*>(h + (size_t)d7.x * D)[lane];
        float w0 = __int_as_float(d0.y), w1 = __int_as_float(d1.y);
        float w2 = __int_as_float(d2.y), w3 = __int_as_float(d3.y);
        float w4 = __int_as_float(d4.y), w5 = __int_as_float(d5.y);
        float w6 = __int_as_float(d6.y), w7 = __int_as_float(d7.y);
        acc.x = fmaf(v0.x, w0, acc.x); acc.y = fmaf(v0.y, w0, acc.y);
        acc.z = fmaf(v0.z, w0, acc.z); acc.w = fmaf(v0.w, w0, acc.w);
        acc.x = fmaf(v1.x, w1, acc.x); acc.y = fmaf(v1.y, w1, acc.y);
        acc.z = fmaf(v1.z, w1, acc.z); acc.w = fmaf(v1.w, w1, acc.w);
        acc.x = fmaf(v2.x, w2, acc.x); acc.y = fmaf(v2.y, w2, acc.y);
        acc.z = fmaf(v2.z, w2, acc.z); acc.w = fmaf(v2.w, w2, acc.w);
        acc.x = fmaf(v3.x, w3, acc.x); acc.y = fmaf(v3.y, w3, acc.y);
        acc.z = fmaf(v3.z, w3, acc.z); acc.w = fmaf(v3.w, w3, acc.w);
        acc.x = fmaf(v4.x, w4, acc.x); acc.y = fmaf(v4.y, w4, acc.y);
        acc.z = fmaf(v4.z, w4, acc.z); acc.w = fmaf(v4.w, w4, acc.w);
        acc.x = fmaf(v5.x, w5, acc.x); acc.y = fmaf(v5.y, w5, acc.y);
        acc.z = fmaf(v5.z, w5, acc.z); acc.w = fmaf(v5.w, w5, acc.w);
        acc.x = fmaf(v6.x, w6, acc.x); acc.y = fmaf(v6.y, w6, acc.y);
        acc.z = fmaf(v6.z, w6, acc.z); acc.w = fmaf(v6.w, w6, acc.w);
        acc.x = fmaf(v7.x, w7, acc.x); acc.y = fmaf(v7.y, w7, acc.y);
        acc.z = fmaf(v7.z, w7, acc.z); acc.w = fmaf(v7.w, w7, acc.w);
    }
    for (; e < e1; ++e) {
        int2 dd = edat[e];
        float w = __int_as_float(dd.y);
        float4 v = reinterpret_cast<const float4*>(h + (size_t)dd.x * D)[lane];
        acc.x = fmaf(v.x, w, acc.x); acc.y = fmaf(v.y, w, acc.y);
        acc.z = fmaf(v.z, w, acc.z); acc.w = fmaf(v.w, w, acc.w);
    }
    float4 b4 = reinterpret_cast<const float4*>(bias)[lane];
    acc.x = fmaxf(acc.x + b4.x, 0.f);
    acc.y = fmaxf(acc.y + b4.y, 0.f);
    acc.z = fmaxf(acc.z + b4.z, 0.f);
    acc.w = fmaxf(acc.w + b4.w, 0.f);
    reinterpret_cast<float4*>(out + (size_t)node * D)[lane] = acc;
}

// ---------------- mean-pool: 8 chunks per graph, atomic accumulate ----------------
__global__ __launch_bounds__(256) void pool_kernel(const float* __restrict__ h,
                                                   const int* __restrict__ batch,
                                                   float* __restrict__ pooled) {
    int g = blockIdx.x >> 3;
    int c = blockIdx.x & 7;
    int tid = threadIdx.x, w = tid >> 6, lane = tid & 63;
    int lo = 0, hi = N_NODES;
    while (lo < hi) { int m = (lo + hi) >> 1; if (batch[m] < g) lo = m + 1; else hi = m; }
    int start = lo;
    hi = N_NODES;
    while (lo < hi) { int m = (lo + hi) >> 1; if (batch[m] <= g) lo = m + 1; else hi = m; }
    int end = lo;
    float4 acc = make_float4(0.f, 0.f, 0.f, 0.f);
    for (int nd = start + c + 8 * w; nd < end; nd += 32) {
        float4 v = reinterpret_cast<const float4*>(h + (size_t)nd * D)[lane];
        acc.x += v.x; acc.y += v.y; acc.z += v.z; acc.w += v.w;
    }
    float* pg = pooled + g * D + (lane << 2);
    atomicAdd(pg + 0, acc.x);
    atomicAdd(pg + 1, acc.y);
    atomicAdd(pg + 2, acc.z);
    atomicAdd(pg + 3, acc.w);
}

// ---------------- head: out[G,128] = (pooled/count) @ lin_w + lin_b ----------------
__global__ void final_kernel(const float* __restrict__ pooled, const int* __restrict__ batch,
                             const float* __restrict__ lw, const float* __restrict__ lb,
                             float* __restrict__ out) {
    int g = blockIdx.x;
    int j = threadIdx.x;  // 128 threads
    __shared__ float p[D];
    int lo = 0, hi = N_NODES;
    while (lo < hi) { int m = (lo + hi) >> 1; if (batch[m] < g) lo = m + 1; else hi = m; }
    int start = lo;
    hi = N_NODES;
    while (lo < hi) { int m = (lo + hi) >> 1; if (batch[m] <= g) lo = m + 1; else hi = m; }
    int cntg = lo - start;
    float inv = 1.f / (float)(cntg > 0 ? cntg : 1);
    p[j] = pooled[g * D + j] * inv;
    p[j + 128] = pooled[g * D + j + 128] * inv;
    __syncthreads();
    float acc = lb[j];
    for (int k = 0; k < D; ++k) acc = fmaf(p[k], lw[k * N_TASKS + j], acc);
    out[g * N_TASKS + j] = acc;
}

extern "C" void kernel_launch(void* const* d_in, const int* in_sizes, int n_in,
                              void* d_out, int out_size, void* d_ws, size_t ws_size,
                              hipStream_t stream) {
    const float* x   = (const float*)d_in[0];
    const int*   ei  = (const int*)d_in[1];
    const int*   bat = (const int*)d_in[2];
    const float* W1  = (const float*)d_in[3];
    const float* b1  = (const float*)d_in[4];
    const float* W2  = (const float*)d_in[5];
    const float* b2  = (const float*)d_in[6];
    const float* W3  = (const float*)d_in[7];
    const float* b3  = (const float*)d_in[8];
    const float* lw  = (const float*)d_in[9];
    const float* lb  = (const float*)d_in[10];
    float* out = (float*)d_out;

    const int* src = ei;
    const int* dst = ei + N_EDGES;

    char* ws = (char*)d_ws;
    float* hA     = (float*)(ws + 0);                 // 10,240,000 B
    float* hB     = (float*)(ws + 10240000);          // 10,240,000 B
    float* pooled = (float*)(ws + 20480000);          //    131,072 B
    float* isd    = (float*)(ws + 20611072);          //     40,000 B
    int*   cnt    = (int*)  (ws + 20651072);          //     40,000 B
    int*   fill   = (int*)  (ws + 20691072);          //     40,000 B
    int*   rowptr = (int*)  (ws + 20731072);          //     40,016 B
    int2*  edat   = (int2*) (ws + 20771088);          //  2,560,000 B (total ~23.3 MB)

    // CSR build (once per call)
    init_kernel<<<128, 256, 0, stream>>>(cnt, fill, pooled);
    hist_kernel<<<(N_EDGES + 255) / 256, 256, 0, stream>>>(dst, cnt);
    scan_kernel<<<1, 256, 0, stream>>>(cnt, rowptr, isd);
    fillcsr_kernel<<<(N_EDGES + 255) / 256, 256, 0, stream>>>(src, dst, rowptr, isd, fill, edat);

    dim3 mmgrid((N_NODES + BM - 1) / BM, D / BN);   // 157 x 4 = 628 blocks
    const int AGG_BLOCKS = N_NODES / 4;             // 2500 (4 waves/block, 1 node/wave)

    // Layer 1
    matmul_kernel<<<mmgrid, 256, 0, stream>>>(x, W1, hB);
    agg_kernel<<<AGG_BLOCKS, 256, 0, stream>>>(hB, rowptr, edat, isd, b1, hA);
    // Layer 2
    matmul_kernel<<<mmgrid, 256, 0, stream>>>(hA, W2, hB);
    agg_kernel<<<AGG_BLOCKS, 256, 0, stream>>>(hB, rowptr, edat, isd, b2, hA);
    // Layer 3
    matmul_kernel<<<mmgrid, 256, 0, stream>>>(hA, W3, hB);
    agg_kernel<<<AGG_BLOCKS, 256, 0, stream>>>(hB, rowptr, edat, isd, b3, hA);

    // Pool + head
    pool_kernel<<<N_GRAPHS * 8, 256, 0, stream>>>(hA, bat, pooled);
    final_kernel<<<N_GRAPHS, 128, 0, stream>>>(pooled, bat, lw, lb, out);
}

// Round 4
// 271.449 us; speedup vs baseline: 1.8038x; 1.1114x over previous
//
#include <hip/hip_runtime.h>

#define N_NODES  10000
#define N_EDGES  320000
#define D        256
#define N_TASKS  128
#define N_GRAPHS 128

typedef __attribute__((ext_vector_type(8))) short short8;
typedef __attribute__((ext_vector_type(4))) float floatx4;

__device__ __forceinline__ unsigned short f2bf(float f) {
    unsigned u = __float_as_uint(f);
    u += 0x7FFF + ((u >> 16) & 1);   // RNE
    return (unsigned short)(u >> 16);
}
__device__ __forceinline__ float bf2f(unsigned short h) {
    return __uint_as_float(((unsigned)h) << 16);
}

// ---------------- CSR build ----------------

__global__ void init_kernel(int* __restrict__ cnt, int* __restrict__ fill,
                            float* __restrict__ pooled) {
    int i = blockIdx.x * blockDim.x + threadIdx.x;
    if (i < N_NODES) { cnt[i] = 1; fill[i] = 0; }   // cnt starts at 1: self-loop
    if (i < N_GRAPHS * D) pooled[i] = 0.f;          // zero pool accumulators
}

__global__ void hist_kernel(const int* __restrict__ dst, int* __restrict__ cnt) {
    int e = blockIdx.x * blockDim.x + threadIdx.x;
    if (e < N_EDGES) atomicAdd(&cnt[dst[e]], 1);
}

__global__ __launch_bounds__(256) void scan_kernel(const int* __restrict__ cnt,
                                                   int* __restrict__ rowptr,
                                                   float* __restrict__ isd) {
    __shared__ int scnt[10240];
    __shared__ int part[256];
    const int CH = 40;
    int t = threadIdx.x;
    for (int i = t; i < 10240; i += 256) scnt[i] = (i < N_NODES) ? cnt[i] : 1;
    __syncthreads();
    int base = t * CH;
    int s = 0;
#pragma unroll 8
    for (int i = 0; i < CH; ++i) s += scnt[base + i] - 1;
    part[t] = s;
    __syncthreads();
    for (int off = 1; off < 256; off <<= 1) {
        int v = (t >= off) ? part[t - off] : 0;
        __syncthreads();
        part[t] += v;
        __syncthreads();
    }
    int run = (t == 0) ? 0 : part[t - 1];
    for (int i = 0; i < CH; ++i) {
        int idx = base + i;
        if (idx < N_NODES) {
            rowptr[idx] = run;
            int c = scnt[idx];
            run += c - 1;
            isd[idx] = rsqrtf((float)c);
        }
    }
    if (t == 255) rowptr[N_NODES] = run;
}

__global__ void fillcsr_kernel(const int* __restrict__ src, const int* __restrict__ dst,
                               const int* __restrict__ rowptr, const float* __restrict__ isd,
                               int* __restrict__ fill, int2* __restrict__ edat) {
    int e = blockIdx.x * blockDim.x + threadIdx.x;
    if (e < N_EDGES) {
        int s = src[e], d = dst[e];
        int pos = rowptr[d] + atomicAdd(&fill[d], 1);
        edat[pos] = make_int2(s, __float_as_int(isd[s] * isd[d]));
    }
}

// ---------------- split f32 -> bf16 hi/lo planes ----------------

__global__ __launch_bounds__(256) void split_kernel(const float* __restrict__ in,
                                                    unsigned short* __restrict__ hi,
                                                    unsigned short* __restrict__ lo) {
    int i = blockIdx.x * blockDim.x + threadIdx.x;  // over N_NODES*D/4
    if (i >= N_NODES * D / 4) return;
    float4 v = reinterpret_cast<const float4*>(in)[i];
    ushort4 h, l;
    h.x = f2bf(v.x); l.x = f2bf(v.x - bf2f(h.x));
    h.y = f2bf(v.y); l.y = f2bf(v.y - bf2f(h.y));
    h.z = f2bf(v.z); l.z = f2bf(v.z - bf2f(h.z));
    h.w = f2bf(v.w); l.w = f2bf(v.w - bf2f(h.w));
    reinterpret_cast<ushort4*>(hi)[i] = h;
    reinterpret_cast<ushort4*>(lo)[i] = l;
}

// W[k][n] f32 -> Wt_hi/lo[n][k] bf16 (transposed so mm's b-frag is contiguous)
__global__ __launch_bounds__(256) void wsplit_kernel(const float* __restrict__ W1,
                                                     const float* __restrict__ W2,
                                                     const float* __restrict__ W3,
                                                     unsigned short* __restrict__ wth,
                                                     unsigned short* __restrict__ wtl) {
    __shared__ float t[32][33];
    int b = blockIdx.x;                 // 3*64 blocks
    int w = b >> 6, tile = b & 63;
    int kt = (tile >> 3) << 5, nt = (tile & 7) << 5;
    const float* W = (w == 0) ? W1 : (w == 1) ? W2 : W3;
    int tid = threadIdx.x, r = tid >> 5, c = tid & 31;
#pragma unroll
    for (int i = 0; i < 4; ++i)
        t[r + 8 * i][c] = W[(size_t)(kt + r + 8 * i) * D + nt + c];
    __syncthreads();
    unsigned short* oh = wth + w * D * D;
    unsigned short* ol = wtl + w * D * D;
#pragma unroll
    for (int i = 0; i < 4; ++i) {
        float v = t[c][r + 8 * i];      // = W[kt+c][nt+r+8i]
        unsigned short hv = f2bf(v);
        oh[(size_t)(nt + r + 8 * i) * D + kt + c] = hv;
        ol[(size_t)(nt + r + 8 * i) * D + kt + c] = f2bf(v - bf2f(hv));
    }
}

// ---------------- MFMA matmul: C[N,256] = (Ah+Al) @ (Wh+Wl), 3-plane product ----
// 64x64 tile, BK=32 (one MFMA k-slice), 4 waves 2x2, wave-tile 32x32.
__global__ __launch_bounds__(256) void mm_kernel(const unsigned short* __restrict__ Ah,
                                                 const unsigned short* __restrict__ Al,
                                                 const unsigned short* __restrict__ Wh,
                                                 const unsigned short* __restrict__ Wl,
                                                 float* __restrict__ C) {
    __shared__ unsigned short sAh[64][40], sAl[64][40], sWh[64][40], sWl[64][40];
    int tid = threadIdx.x;
    int lane = tid & 63, wid = tid >> 6;
    int wr = wid >> 1, wc = wid & 1;
    int row0 = blockIdx.x << 6;
    int n0 = blockIdx.y << 6;

    int sr = tid >> 2;              // 0..63 tile row
    int sk = (tid & 3) << 3;        // 0,8,16,24 k elems
    int arow = row0 + sr; if (arow >= N_NODES) arow = N_NODES - 1;  // clamp; stores guarded
    const unsigned short* pAh = Ah + (size_t)arow * D + sk;
    const unsigned short* pAl = Al + (size_t)arow * D + sk;
    const unsigned short* pWh = Wh + (size_t)(n0 + sr) * D + sk;
    const unsigned short* pWl = Wl + (size_t)(n0 + sr) * D + sk;

    uint4 rAh = *(const uint4*)pAh;
    uint4 rAl = *(const uint4*)pAl;
    uint4 rWh = *(const uint4*)pWh;
    uint4 rWl = *(const uint4*)pWl;

    int fr = lane & 15;             // row (A) / col (B)
    int fk = (lane >> 4) << 3;      // k offset

    floatx4 acc00 = {0.f, 0.f, 0.f, 0.f};
    floatx4 acc01 = acc00, acc10 = acc00, acc11 = acc00;

#pragma unroll 1
    for (int step = 0; step < D / 32; ++step) {
        *(uint4*)&sAh[sr][sk] = rAh;
        *(uint4*)&sAl[sr][sk] = rAl;
        *(uint4*)&sWh[sr][sk] = rWh;
        *(uint4*)&sWl[sr][sk] = rWl;
        __syncthreads();
        if (step < D / 32 - 1) {    // prefetch next k-slice
            rAh = *(const uint4*)(pAh + (step + 1) * 32);
            rAl = *(const uint4*)(pAl + (step + 1) * 32);
            rWh = *(const uint4*)(pWh + (step + 1) * 32);
            rWl = *(const uint4*)(pWl + (step + 1) * 32);
        }
        short8 ah0 = *(const short8*)&sAh[(wr << 5) + fr][fk];
        short8 ah1 = *(const short8*)&sAh[(wr << 5) + 16 + fr][fk];
        short8 al0 = *(const short8*)&sAl[(wr << 5) + fr][fk];
        short8 al1 = *(const short8*)&sAl[(wr << 5) + 16 + fr][fk];
        short8 bh0 = *(const short8*)&sWh[(wc << 5) + fr][fk];
        short8 bh1 = *(const short8*)&sWh[(wc << 5) + 16 + fr][fk];
        short8 bl0 = *(const short8*)&sWl[(wc << 5) + fr][fk];
        short8 bl1 = *(const short8*)&sWl[(wc << 5) + 16 + fr][fk];
        acc00 = __builtin_amdgcn_mfma_f32_16x16x32_bf16(ah0, bh0, acc00, 0, 0, 0);
        acc00 = __builtin_amdgcn_mfma_f32_16x16x32_bf16(ah0, bl0, acc00, 0, 0, 0);
        acc00 = __builtin_amdgcn_mfma_f32_16x16x32_bf16(al0, bh0, acc00, 0, 0, 0);
        acc01 = __builtin_amdgcn_mfma_f32_16x16x32_bf16(ah0, bh1, acc01, 0, 0, 0);
        acc01 = __builtin_amdgcn_mfma_f32_16x16x32_bf16(ah0, bl1, acc01, 0, 0, 0);
        acc01 = __builtin_amdgcn_mfma_f32_16x16x32_bf16(al0, bh1, acc01, 0, 0, 0);
        acc10 = __builtin_amdgcn_mfma_f32_16x16x32_bf16(ah1, bh0, acc10, 0, 0, 0);
        acc10 = __builtin_amdgcn_mfma_f32_16x16x32_bf16(ah1, bl0, acc10, 0, 0, 0);
        acc10 = __builtin_amdgcn_mfma_f32_16x16x32_bf16(al1, bh0, acc10, 0, 0, 0);
        acc11 = __builtin_amdgcn_mfma_f32_16x16x32_bf16(ah1, bh1, acc11, 0, 0, 0);
        acc11 = __builtin_amdgcn_mfma_f32_16x16x32_bf16(ah1, bl1, acc11, 0, 0, 0);
        acc11 = __builtin_amdgcn_mfma_f32_16x16x32_bf16(al1, bh1, acc11, 0, 0, 0);
        __syncthreads();
    }

    // C/D layout: col = lane&15, row = (lane>>4)*4 + reg   [m89-verified]
    int crow = (lane >> 4) << 2;
    int colbase = n0 + (wc << 5) + fr;
#pragma unroll
    for (int r = 0; r < 4; ++r) {
        int gr0 = row0 + (wr << 5) + crow + r;
        if (gr0 < N_NODES) {
            C[(size_t)gr0 * D + colbase]      = acc00[r];
            C[(size_t)gr0 * D + colbase + 16] = acc01[r];
        }
        int gr1 = gr0 + 16;
        if (gr1 < N_NODES) {
            C[(size_t)gr1 * D + colbase]      = acc10[r];
            C[(size_t)gr1 * D + colbase + 16] = acc11[r];
        }
    }
}

// ---------------- aggregation: out[i] = relu(b + sum_{e: dst=i} h[src]*w) --------
// SPLIT=1: write bf16 hi/lo planes (feeds next mm); SPLIT=0: write f32 (feeds pool).
template <int SPLIT>
__global__ __launch_bounds__(256) void agg_kernel(const float* __restrict__ h,
                                                  const int* __restrict__ rowptr,
                                                  const int2* __restrict__ edat,
                                                  const float* __restrict__ isd,
                                                  const float* __restrict__ bias,
                                                  float* __restrict__ outf,
                                                  unsigned short* __restrict__ ohi,
                                                  unsigned short* __restrict__ olo) {
    int wave = (blockIdx.x * blockDim.x + threadIdx.x) >> 6;
    int lane = threadIdx.x & 63;
    if (wave >= N_NODES) return;
    int node = wave;
    float isd_i = isd[node];
    float selfn = isd_i * isd_i;
    float4 a = reinterpret_cast<const float4*>(h + (size_t)node * D)[lane];
    float4 acc = make_float4(a.x * selfn, a.y * selfn, a.z * selfn, a.w * selfn);
    int e0 = rowptr[node], e1 = rowptr[node + 1];
    int e = e0;
    for (; e + 8 <= e1; e += 8) {
        int2 d0 = edat[e + 0]; int2 d1 = edat[e + 1];
        int2 d2 = edat[e + 2]; int2 d3 = edat[e + 3];
        int2 d4 = edat[e + 4]; int2 d5 = edat[e + 5];
        int2 d6 = edat[e + 6]; int2 d7 = edat[e + 7];
        float4 v0 = reinterpret_cast<const float4*>(h + (size_t)d0.x * D)[lane];
        float4 v1 = reinterpret_cast<const float4*>(h + (size_t)d1.x * D)[lane];
        float4 v2 = reinterpret_cast<const float4*>(h + (size_t)d2.x * D)[lane];
        float4 v3 = reinterpret_cast<const float4*>(h + (size_t)d3.x * D)[lane];
        float4 v4 = reinterpret_cast<const float4*>(h + (size_t)d4.x * D)[lane];
        float4 v5 = reinterpret_cast<const float4*>(h + (size_t)d5.x * D)[lane];
        float4 v6 = reinterpret_cast<const float4*>(h + (size_t)d6.x * D)[lane];
        float4 v7 = reinterpret_cast<const float4*>(h + (size_t)d7.x * D)[lane];
        float w0 = __int_as_float(d0.y), w1 = __int_as_float(d1.y);
        float w2 = __int_as_float(d2.y), w3 = __int_as_float(d3.y);
        float w4 = __int_as_float(d4.y), w5 = __int_as_float(d5.y);
        float w6 = __int_as_float(d6.y), w7 = __int_as_float(d7.y);
        acc.x = fmaf(v0.x, w0, acc.x); acc.y = fmaf(v0.y, w0, acc.y);
        acc.z = fmaf(v0.z, w0, acc.z); acc.w = fmaf(v0.w, w0, acc.w);
        acc.x = fmaf(v1.x, w1, acc.x); acc.y = fmaf(v1.y, w1, acc.y);
        acc.z = fmaf(v1.z, w1, acc.z); acc.w = fmaf(v1.w, w1, acc.w);
        acc.x = fmaf(v2.x, w2, acc.x); acc.y = fmaf(v2.y, w2, acc.y);
        acc.z = fmaf(v2.z, w2, acc.z); acc.w = fmaf(v2.w, w2, acc.w);
        acc.x = fmaf(v3.x, w3, acc.x); acc.y = fmaf(v3.y, w3, acc.y);
        acc.z = fmaf(v3.z, w3, acc.z); acc.w = fmaf(v3.w, w3, acc.w);
        acc.x = fmaf(v4.x, w4, acc.x); acc.y = fmaf(v4.y, w4, acc.y);
        acc.z = fmaf(v4.z, w4, acc.z); acc.w = fmaf(v4.w, w4, acc.w);
        acc.x = fmaf(v5.x, w5, acc.x); acc.y = fmaf(v5.y, w5, acc.y);
        acc.z = fmaf(v5.z, w5, acc.z); acc.w = fmaf(v5.w, w5, acc.w);
        acc.x = fmaf(v6.x, w6, acc.x); acc.y = fmaf(v6.y, w6, acc.y);
        acc.z = fmaf(v6.z, w6, acc.z); acc.w = fmaf(v6.w, w6, acc.w);
        acc.x = fmaf(v7.x, w7, acc.x); acc.y = fmaf(v7.y, w7, acc.y);
        acc.z = fmaf(v7.z, w7, acc.z); acc.w = fmaf(v7.w, w7, acc.w);
    }
    for (; e < e1; ++e) {
        int2 dd = edat[e];
        float w = __int_as_float(dd.y);
        float4 v = reinterpret_cast<const float4*>(h + (size_t)dd.x * D)[lane];
        acc.x = fmaf(v.x, w, acc.x); acc.y = fmaf(v.y, w, acc.y);
        acc.z = fmaf(v.z, w, acc.z); acc.w = fmaf(v.w, w, acc.w);
    }
    float4 b4 = reinterpret_cast<const float4*>(bias)[lane];
    acc.x = fmaxf(acc.x + b4.x, 0.f);
    acc.y = fmaxf(acc.y + b4.y, 0.f);
    acc.z = fmaxf(acc.z + b4.z, 0.f);
    acc.w = fmaxf(acc.w + b4.w, 0.f);
    if (SPLIT) {
        ushort4 hh, ll;
        hh.x = f2bf(acc.x); ll.x = f2bf(acc.x - bf2f(hh.x));
        hh.y = f2bf(acc.y); ll.y = f2bf(acc.y - bf2f(hh.y));
        hh.z = f2bf(acc.z); ll.z = f2bf(acc.z - bf2f(hh.z));
        hh.w = f2bf(acc.w); ll.w = f2bf(acc.w - bf2f(hh.w));
        reinterpret_cast<ushort4*>(ohi + (size_t)node * D)[lane] = hh;
        reinterpret_cast<ushort4*>(olo + (size_t)node * D)[lane] = ll;
    } else {
        reinterpret_cast<float4*>(outf + (size_t)node * D)[lane] = acc;
    }
}

// ---------------- mean-pool: 8 chunks per graph, atomic accumulate ----------------
__global__ __launch_bounds__(256) void pool_kernel(const float* __restrict__ h,
                                                   const int* __restrict__ batch,
                                                   float* __restrict__ pooled) {
    int g = blockIdx.x >> 3;
    int c = blockIdx.x & 7;
    int tid = threadIdx.x, w = tid >> 6, lane = tid & 63;
    int lo = 0, hi = N_NODES;
    while (lo < hi) { int m = (lo + hi) >> 1; if (batch[m] < g) lo = m + 1; else hi = m; }
    int start = lo;
    hi = N_NODES;
    while (lo < hi) { int m = (lo + hi) >> 1; if (batch[m] <= g) lo = m + 1; else hi = m; }
    int end = lo;
    float4 acc = make_float4(0.f, 0.f, 0.f, 0.f);
    for (int nd = start + c + 8 * w; nd < end; nd += 32) {
        float4 v = reinterpret_cast<const float4*>(h + (size_t)nd * D)[lane];
        acc.x += v.x; acc.y += v.y; acc.z += v.z; acc.w += v.w;
    }
    float* pg = pooled + g * D + (lane << 2);
    atomicAdd(pg + 0, acc.x);
    atomicAdd(pg + 1, acc.y);
    atomicAdd(pg + 2, acc.z);
    atomicAdd(pg + 3, acc.w);
}

// ---------------- head ----------------
__global__ void final_kernel(const float* __restrict__ pooled, const int* __restrict__ batch,
                             const float* __restrict__ lw, const float* __restrict__ lb,
                             float* __restrict__ out) {
    int g = blockIdx.x;
    int j = threadIdx.x;
    __shared__ float p[D];
    int lo = 0, hi = N_NODES;
    while (lo < hi) { int m = (lo + hi) >> 1; if (batch[m] < g) lo = m + 1; else hi = m; }
    int start = lo;
    hi = N_NODES;
    while (lo < hi) { int m = (lo + hi) >> 1; if (batch[m] <= g) lo = m + 1; else hi = m; }
    int cntg = lo - start;
    float inv = 1.f / (float)(cntg > 0 ? cntg : 1);
    p[j] = pooled[g * D + j] * inv;
    p[j + 128] = pooled[g * D + j + 128] * inv;
    __syncthreads();
    float acc = lb[j];
    for (int k = 0; k < D; ++k) acc = fmaf(p[k], lw[k * N_TASKS + j], acc);
    out[g * N_TASKS + j] = acc;
}

extern "C" void kernel_launch(void* const* d_in, const int* in_sizes, int n_in,
                              void* d_out, int out_size, void* d_ws, size_t ws_size,
                              hipStream_t stream) {
    const float* x   = (const float*)d_in[0];
    const int*   ei  = (const int*)d_in[1];
    const int*   bat = (const int*)d_in[2];
    const float* W1  = (const float*)d_in[3];
    const float* b1  = (const float*)d_in[4];
    const float* W2  = (const float*)d_in[5];
    const float* b2  = (const float*)d_in[6];
    const float* W3  = (const float*)d_in[7];
    const float* b3  = (const float*)d_in[8];
    const float* lw  = (const float*)d_in[9];
    const float* lb  = (const float*)d_in[10];
    float* out = (float*)d_out;

    const int* src = ei;
    const int* dst = ei + N_EDGES;

    char* ws = (char*)d_ws;
    float*          hC     = (float*)         (ws + 0);          // 10,240,000
    float*          hA     = (float*)         (ws + 10240000);   // 10,240,000
    unsigned short* Ah     = (unsigned short*)(ws + 20480000);   //  5,120,000
    unsigned short* Al     = (unsigned short*)(ws + 25600000);   //  5,120,000
    unsigned short* Wth    = (unsigned short*)(ws + 30720000);   //    393,216
    unsigned short* Wtl    = (unsigned short*)(ws + 31113216);   //    393,216
    float*          pooled = (float*)         (ws + 31506432);   //    131,072
    float*          isd    = (float*)         (ws + 31637504);   //     40,000
    int*            cnt    = (int*)           (ws + 31677504);   //     40,000
    int*            fill   = (int*)           (ws + 31717504);   //     40,000
    int*            rowptr = (int*)           (ws + 31757504);   //     40,016
    int2*           edat   = (int2*)          (ws + 31797520);   //  2,560,000  (~34.4 MB)

    // CSR build + weight/x split (once per call)
    init_kernel<<<128, 256, 0, stream>>>(cnt, fill, pooled);
    hist_kernel<<<(N_EDGES + 255) / 256, 256, 0, stream>>>(dst, cnt);
    scan_kernel<<<1, 256, 0, stream>>>(cnt, rowptr, isd);
    fillcsr_kernel<<<(N_EDGES + 255) / 256, 256, 0, stream>>>(src, dst, rowptr, isd, fill, edat);
    wsplit_kernel<<<3 * 64, 256, 0, stream>>>(W1, W2, W3, Wth, Wtl);
    split_kernel<<<(N_NODES * D / 4 + 255) / 256, 256, 0, stream>>>(x, Ah, Al);

    dim3 mmgrid((N_NODES + 63) / 64, D / 64);   // 157 x 4
    const int AGG_BLOCKS = N_NODES / 4;         // 2500

    // Layer 1
    mm_kernel<<<mmgrid, 256, 0, stream>>>(Ah, Al, Wth, Wtl, hC);
    agg_kernel<1><<<AGG_BLOCKS, 256, 0, stream>>>(hC, rowptr, edat, isd, b1, nullptr, Ah, Al);
    // Layer 2
    mm_kernel<<<mmgrid, 256, 0, stream>>>(Ah, Al, Wth + D * D, Wtl + D * D, hC);
    agg_kernel<1><<<AGG_BLOCKS, 256, 0, stream>>>(hC, rowptr, edat, isd, b2, nullptr, Ah, Al);
    // Layer 3
    mm_kernel<<<mmgrid, 256, 0, stream>>>(Ah, Al, Wth + 2 * D * D, Wtl + 2 * D * D, hC);
    agg_kernel<0><<<AGG_BLOCKS, 256, 0, stream>>>(hC, rowptr, edat, isd, b3, hA, nullptr, nullptr);

    // Pool + head
    pool_kernel<<<N_GRAPHS * 8, 256, 0, stream>>>(hA, bat, pooled);
    final_kernel<<<N_GRAPHS, 128, 0, stream>>>(pooled, bat, lw, lb, out);
}

// Round 5
// 241.024 us; speedup vs baseline: 2.0315x; 1.1262x over previous
//
#include <hip/hip_runtime.h>

#define N_NODES  10000
#define N_EDGES  320000
#define D        256
#define N_TASKS  128
#define N_GRAPHS 128

#define CSR_BLOCKS 256
#define EPB (N_EDGES / CSR_BLOCKS)   // 1250 edges per block

typedef __attribute__((ext_vector_type(8))) short short8;
typedef __attribute__((ext_vector_type(4))) float floatx4;

__device__ __forceinline__ unsigned short f2bf(float f) {
    unsigned u = __float_as_uint(f);
    u += 0x7FFF + ((u >> 16) & 1);   // RNE
    return (unsigned short)(u >> 16);
}
__device__ __forceinline__ float bf2f(unsigned short h) {
    return __uint_as_float(((unsigned)h) << 16);
}

// ---------------- misc init ----------------

__global__ void init_kernel(float* __restrict__ pooled) {
    int i = blockIdx.x * blockDim.x + threadIdx.x;
    if (i < N_GRAPHS * D) pooled[i] = 0.f;
}

// ---------------- CSR build, atomic-free (LDS-privatized counting sort) --------

// Pass 1: per-block LDS histogram of dst, flushed to histbuf[b][n].
__global__ __launch_bounds__(256) void histp_kernel(const int* __restrict__ dst,
                                                    int* __restrict__ histbuf) {
    __shared__ int h[N_NODES];   // 40 KB
    int b = blockIdx.x, t = threadIdx.x;
    for (int i = t; i < N_NODES; i += 256) h[i] = 0;
    __syncthreads();
    int e0 = b * EPB;
    for (int i = t; i < EPB; i += 256) atomicAdd(&h[dst[e0 + i]], 1);
    __syncthreads();
    int* out = histbuf + (size_t)b * N_NODES;
    for (int i = t; i < N_NODES; i += 256) out[i] = h[i];
}

// Pass 2: per node, running sum over 256 block-rows -> exclusive per-block
// prefixes (in place) + total count (+1 self-loop). 8-deep load pipelining.
__global__ __launch_bounds__(256) void merge_kernel(int* __restrict__ histbuf,
                                                    int* __restrict__ cnt) {
    int n = blockIdx.x * 256 + threadIdx.x;
    if (n >= N_NODES) return;
    int run = 0;
#pragma unroll 1
    for (int b = 0; b < CSR_BLOCKS; b += 8) {
        int v0 = histbuf[(size_t)(b + 0) * N_NODES + n];
        int v1 = histbuf[(size_t)(b + 1) * N_NODES + n];
        int v2 = histbuf[(size_t)(b + 2) * N_NODES + n];
        int v3 = histbuf[(size_t)(b + 3) * N_NODES + n];
        int v4 = histbuf[(size_t)(b + 4) * N_NODES + n];
        int v5 = histbuf[(size_t)(b + 5) * N_NODES + n];
        int v6 = histbuf[(size_t)(b + 6) * N_NODES + n];
        int v7 = histbuf[(size_t)(b + 7) * N_NODES + n];
        histbuf[(size_t)(b + 0) * N_NODES + n] = run; run += v0;
        histbuf[(size_t)(b + 1) * N_NODES + n] = run; run += v1;
        histbuf[(size_t)(b + 2) * N_NODES + n] = run; run += v2;
        histbuf[(size_t)(b + 3) * N_NODES + n] = run; run += v3;
        histbuf[(size_t)(b + 4) * N_NODES + n] = run; run += v4;
        histbuf[(size_t)(b + 5) * N_NODES + n] = run; run += v5;
        histbuf[(size_t)(b + 6) * N_NODES + n] = run; run += v6;
        histbuf[(size_t)(b + 7) * N_NODES + n] = run; run += v7;
    }
    cnt[n] = run + 1;   // +1: self-loop
}

// Pass 3 (after scan): node-scan of (cnt-1) -> rowptr; isd = rsqrt(cnt).
__global__ __launch_bounds__(256) void scan_kernel(const int* __restrict__ cnt,
                                                   int* __restrict__ rowptr,
                                                   float* __restrict__ isd) {
    __shared__ int scnt[10240];
    __shared__ int part[256];
    const int CH = 40;
    int t = threadIdx.x;
    for (int i = t; i < 10240; i += 256) scnt[i] = (i < N_NODES) ? cnt[i] : 1;
    __syncthreads();
    int base = t * CH;
    int s = 0;
#pragma unroll 8
    for (int i = 0; i < CH; ++i) s += scnt[base + i] - 1;
    part[t] = s;
    __syncthreads();
    for (int off = 1; off < 256; off <<= 1) {
        int v = (t >= off) ? part[t - off] : 0;
        __syncthreads();
        part[t] += v;
        __syncthreads();
    }
    int run = (t == 0) ? 0 : part[t - 1];
    for (int i = 0; i < CH; ++i) {
        int idx = base + i;
        if (idx < N_NODES) {
            rowptr[idx] = run;
            int c = scnt[idx];
            run += c - 1;
            isd[idx] = rsqrtf((float)c);
        }
    }
    if (t == 255) rowptr[N_NODES] = run;
}

// Pass 4: scatter edges to unique CSR slots; rank via LDS atomic (block-local).
__global__ __launch_bounds__(256) void scatter_kernel(const int* __restrict__ src,
                                                      const int* __restrict__ dst,
                                                      const int* __restrict__ rowptr,
                                                      const int* __restrict__ histbuf,
                                                      const float* __restrict__ isd,
                                                      int2* __restrict__ edat) {
    __shared__ int h[N_NODES];   // 40 KB
    int b = blockIdx.x, t = threadIdx.x;
    for (int i = t; i < N_NODES; i += 256) h[i] = 0;
    __syncthreads();
    int e0 = b * EPB;
    const int* bpref = histbuf + (size_t)b * N_NODES;
    for (int i = t; i < EPB; i += 256) {
        int e = e0 + i;
        int s = src[e], d = dst[e];
        int rank = atomicAdd(&h[d], 1);
        int pos = rowptr[d] + bpref[d] + rank;
        edat[pos] = make_int2(s, __float_as_int(isd[s] * isd[d]));
    }
}

// ---------------- split f32 -> bf16 hi/lo planes ----------------

__global__ __launch_bounds__(256) void split_kernel(const float* __restrict__ in,
                                                    unsigned short* __restrict__ hi,
                                                    unsigned short* __restrict__ lo) {
    int i = blockIdx.x * blockDim.x + threadIdx.x;  // over N_NODES*D/4
    if (i >= N_NODES * D / 4) return;
    float4 v = reinterpret_cast<const float4*>(in)[i];
    ushort4 h, l;
    h.x = f2bf(v.x); l.x = f2bf(v.x - bf2f(h.x));
    h.y = f2bf(v.y); l.y = f2bf(v.y - bf2f(h.y));
    h.z = f2bf(v.z); l.z = f2bf(v.z - bf2f(h.z));
    h.w = f2bf(v.w); l.w = f2bf(v.w - bf2f(h.w));
    reinterpret_cast<ushort4*>(hi)[i] = h;
    reinterpret_cast<ushort4*>(lo)[i] = l;
}

// W[k][n] f32 -> Wt_hi/lo[n][k] bf16 (transposed so mm's b-frag is contiguous)
__global__ __launch_bounds__(256) void wsplit_kernel(const float* __restrict__ W1,
                                                     const float* __restrict__ W2,
                                                     const float* __restrict__ W3,
                                                     unsigned short* __restrict__ wth,
                                                     unsigned short* __restrict__ wtl) {
    __shared__ float t[32][33];
    int b = blockIdx.x;                 // 3*64 blocks
    int w = b >> 6, tile = b & 63;
    int kt = (tile >> 3) << 5, nt = (tile & 7) << 5;
    const float* W = (w == 0) ? W1 : (w == 1) ? W2 : W3;
    int tid = threadIdx.x, r = tid >> 5, c = tid & 31;
#pragma unroll
    for (int i = 0; i < 4; ++i)
        t[r + 8 * i][c] = W[(size_t)(kt + r + 8 * i) * D + nt + c];
    __syncthreads();
    unsigned short* oh = wth + w * D * D;
    unsigned short* ol = wtl + w * D * D;
#pragma unroll
    for (int i = 0; i < 4; ++i) {
        float v = t[c][r + 8 * i];      // = W[kt+c][nt+r+8i]
        unsigned short hv = f2bf(v);
        oh[(size_t)(nt + r + 8 * i) * D + kt + c] = hv;
        ol[(size_t)(nt + r + 8 * i) * D + kt + c] = f2bf(v - bf2f(hv));
    }
}

// ---------------- MFMA matmul: C[N,256] = (Ah+Al) @ (Wh+Wl), 3-plane product ----
__global__ __launch_bounds__(256) void mm_kernel(const unsigned short* __restrict__ Ah,
                                                 const unsigned short* __restrict__ Al,
                                                 const unsigned short* __restrict__ Wh,
                                                 const unsigned short* __restrict__ Wl,
                                                 float* __restrict__ C) {
    __shared__ unsigned short sAh[64][40], sAl[64][40], sWh[64][40], sWl[64][40];
    int tid = threadIdx.x;
    int lane = tid & 63, wid = tid >> 6;
    int wr = wid >> 1, wc = wid & 1;
    int row0 = blockIdx.x << 6;
    int n0 = blockIdx.y << 6;

    int sr = tid >> 2;
    int sk = (tid & 3) << 3;
    int arow = row0 + sr; if (arow >= N_NODES) arow = N_NODES - 1;
    const unsigned short* pAh = Ah + (size_t)arow * D + sk;
    const unsigned short* pAl = Al + (size_t)arow * D + sk;
    const unsigned short* pWh = Wh + (size_t)(n0 + sr) * D + sk;
    const unsigned short* pWl = Wl + (size_t)(n0 + sr) * D + sk;

    uint4 rAh = *(const uint4*)pAh;
    uint4 rAl = *(const uint4*)pAl;
    uint4 rWh = *(const uint4*)pWh;
    uint4 rWl = *(const uint4*)pWl;

    int fr = lane & 15;
    int fk = (lane >> 4) << 3;

    floatx4 acc00 = {0.f, 0.f, 0.f, 0.f};
    floatx4 acc01 = acc00, acc10 = acc00, acc11 = acc00;

#pragma unroll 1
    for (int step = 0; step < D / 32; ++step) {
        *(uint4*)&sAh[sr][sk] = rAh;
        *(uint4*)&sAl[sr][sk] = rAl;
        *(uint4*)&sWh[sr][sk] = rWh;
        *(uint4*)&sWl[sr][sk] = rWl;
        __syncthreads();
        if (step < D / 32 - 1) {
            rAh = *(const uint4*)(pAh + (step + 1) * 32);
            rAl = *(const uint4*)(pAl + (step + 1) * 32);
            rWh = *(const uint4*)(pWh + (step + 1) * 32);
            rWl = *(const uint4*)(pWl + (step + 1) * 32);
        }
        short8 ah0 = *(const short8*)&sAh[(wr << 5) + fr][fk];
        short8 ah1 = *(const short8*)&sAh[(wr << 5) + 16 + fr][fk];
        short8 al0 = *(const short8*)&sAl[(wr << 5) + fr][fk];
        short8 al1 = *(const short8*)&sAl[(wr << 5) + 16 + fr][fk];
        short8 bh0 = *(const short8*)&sWh[(wc << 5) + fr][fk];
        short8 bh1 = *(const short8*)&sWh[(wc << 5) + 16 + fr][fk];
        short8 bl0 = *(const short8*)&sWl[(wc << 5) + fr][fk];
        short8 bl1 = *(const short8*)&sWl[(wc << 5) + 16 + fr][fk];
        acc00 = __builtin_amdgcn_mfma_f32_16x16x32_bf16(ah0, bh0, acc00, 0, 0, 0);
        acc00 = __builtin_amdgcn_mfma_f32_16x16x32_bf16(ah0, bl0, acc00, 0, 0, 0);
        acc00 = __builtin_amdgcn_mfma_f32_16x16x32_bf16(al0, bh0, acc00, 0, 0, 0);
        acc01 = __builtin_amdgcn_mfma_f32_16x16x32_bf16(ah0, bh1, acc01, 0, 0, 0);
        acc01 = __builtin_amdgcn_mfma_f32_16x16x32_bf16(ah0, bl1, acc01, 0, 0, 0);
        acc01 = __builtin_amdgcn_mfma_f32_16x16x32_bf16(al0, bh1, acc01, 0, 0, 0);
        acc10 = __builtin_amdgcn_mfma_f32_16x16x32_bf16(ah1, bh0, acc10, 0, 0, 0);
        acc10 = __builtin_amdgcn_mfma_f32_16x16x32_bf16(ah1, bl0, acc10, 0, 0, 0);
        acc10 = __builtin_amdgcn_mfma_f32_16x16x32_bf16(al1, bh0, acc10, 0, 0, 0);
        acc11 = __builtin_amdgcn_mfma_f32_16x16x32_bf16(ah1, bh1, acc11, 0, 0, 0);
        acc11 = __builtin_amdgcn_mfma_f32_16x16x32_bf16(ah1, bl1, acc11, 0, 0, 0);
        acc11 = __builtin_amdgcn_mfma_f32_16x16x32_bf16(al1, bh1, acc11, 0, 0, 0);
        __syncthreads();
    }

    int crow = (lane >> 4) << 2;
    int colbase = n0 + (wc << 5) + fr;
#pragma unroll
    for (int r = 0; r < 4; ++r) {
        int gr0 = row0 + (wr << 5) + crow + r;
        if (gr0 < N_NODES) {
            C[(size_t)gr0 * D + colbase]      = acc00[r];
            C[(size_t)gr0 * D + colbase + 16] = acc01[r];
        }
        int gr1 = gr0 + 16;
        if (gr1 < N_NODES) {
            C[(size_t)gr1 * D + colbase]      = acc10[r];
            C[(size_t)gr1 * D + colbase + 16] = acc11[r];
        }
    }
}

// ---------------- aggregation: out[i] = relu(b + sum_{e: dst=i} h[src]*w) --------
template <int SPLIT>
__global__ __launch_bounds__(256) void agg_kernel(const float* __restrict__ h,
                                                  const int* __restrict__ rowptr,
                                                  const int2* __restrict__ edat,
                                                  const float* __restrict__ isd,
                                                  const float* __restrict__ bias,
                                                  float* __restrict__ outf,
                                                  unsigned short* __restrict__ ohi,
                                                  unsigned short* __restrict__ olo) {
    int wave = (blockIdx.x * blockDim.x + threadIdx.x) >> 6;
    int lane = threadIdx.x & 63;
    if (wave >= N_NODES) return;
    int node = wave;
    float isd_i = isd[node];
    float selfn = isd_i * isd_i;
    float4 a = reinterpret_cast<const float4*>(h + (size_t)node * D)[lane];
    float4 acc = make_float4(a.x * selfn, a.y * selfn, a.z * selfn, a.w * selfn);
    int e0 = rowptr[node], e1 = rowptr[node + 1];
    int e = e0;
    for (; e + 8 <= e1; e += 8) {
        int2 d0 = edat[e + 0]; int2 d1 = edat[e + 1];
        int2 d2 = edat[e + 2]; int2 d3 = edat[e + 3];
        int2 d4 = edat[e + 4]; int2 d5 = edat[e + 5];
        int2 d6 = edat[e + 6]; int2 d7 = edat[e + 7];
        float4 v0 = reinterpret_cast<const float4*>(h + (size_t)d0.x * D)[lane];
        float4 v1 = reinterpret_cast<const float4*>(h + (size_t)d1.x * D)[lane];
        float4 v2 = reinterpret_cast<const float4*>(h + (size_t)d2.x * D)[lane];
        float4 v3 = reinterpret_cast<const float4*>(h + (size_t)d3.x * D)[lane];
        float4 v4 = reinterpret_cast<const float4*>(h + (size_t)d4.x * D)[lane];
        float4 v5 = reinterpret_cast<const float4*>(h + (size_t)d5.x * D)[lane];
        float4 v6 = reinterpret_cast<const float4*>(h + (size_t)d6.x * D)[lane];
        float4 v7 = reinterpret_cast<const float4*>(h + (size_t)d7.x * D)[lane];
        float w0 = __int_as_float(d0.y), w1 = __int_as_float(d1.y);
        float w2 = __int_as_float(d2.y), w3 = __int_as_float(d3.y);
        float w4 = __int_as_float(d4.y), w5 = __int_as_float(d5.y);
        float w6 = __int_as_float(d6.y), w7 = __int_as_float(d7.y);
        acc.x = fmaf(v0.x, w0, acc.x); acc.y = fmaf(v0.y, w0, acc.y);
        acc.z = fmaf(v0.z, w0, acc.z); acc.w = fmaf(v0.w, w0, acc.w);
        acc.x = fmaf(v1.x, w1, acc.x); acc.y = fmaf(v1.y, w1, acc.y);
        acc.z = fmaf(v1.z, w1, acc.z); acc.w = fmaf(v1.w, w1, acc.w);
        acc.x = fmaf(v2.x, w2, acc.x); acc.y = fmaf(v2.y, w2, acc.y);
        acc.z = fmaf(v2.z, w2, acc.z); acc.w = fmaf(v2.w, w2, acc.w);
        acc.x = fmaf(v3.x, w3, acc.x); acc.y = fmaf(v3.y, w3, acc.y);
        acc.z = fmaf(v3.z, w3, acc.z); acc.w = fmaf(v3.w, w3, acc.w);
        acc.x = fmaf(v4.x, w4, acc.x); acc.y = fmaf(v4.y, w4, acc.y);
        acc.z = fmaf(v4.z, w4, acc.z); acc.w = fmaf(v4.w, w4, acc.w);
        acc.x = fmaf(v5.x, w5, acc.x); acc.y = fmaf(v5.y, w5, acc.y);
        acc.z = fmaf(v5.z, w5, acc.z); acc.w = fmaf(v5.w, w5, acc.w);
        acc.x = fmaf(v6.x, w6, acc.x); acc.y = fmaf(v6.y, w6, acc.y);
        acc.z = fmaf(v6.z, w6, acc.z); acc.w = fmaf(v6.w, w6, acc.w);
        acc.x = fmaf(v7.x, w7, acc.x); acc.y = fmaf(v7.y, w7, acc.y);
        acc.z = fmaf(v7.z, w7, acc.z); acc.w = fmaf(v7.w, w7, acc.w);
    }
    for (; e < e1; ++e) {
        int2 dd = edat[e];
        float w = __int_as_float(dd.y);
        float4 v = reinterpret_cast<const float4*>(h + (size_t)dd.x * D)[lane];
        acc.x = fmaf(v.x, w, acc.x); acc.y = fmaf(v.y, w, acc.y);
        acc.z = fmaf(v.z, w, acc.z); acc.w = fmaf(v.w, w, acc.w);
    }
    float4 b4 = reinterpret_cast<const float4*>(bias)[lane];
    acc.x = fmaxf(acc.x + b4.x, 0.f);
    acc.y = fmaxf(acc.y + b4.y, 0.f);
    acc.z = fmaxf(acc.z + b4.z, 0.f);
    acc.w = fmaxf(acc.w + b4.w, 0.f);
    if (SPLIT) {
        ushort4 hh, ll;
        hh.x = f2bf(acc.x); ll.x = f2bf(acc.x - bf2f(hh.x));
        hh.y = f2bf(acc.y); ll.y = f2bf(acc.y - bf2f(hh.y));
        hh.z = f2bf(acc.z); ll.z = f2bf(acc.z - bf2f(hh.z));
        hh.w = f2bf(acc.w); ll.w = f2bf(acc.w - bf2f(hh.w));
        reinterpret_cast<ushort4*>(ohi + (size_t)node * D)[lane] = hh;
        reinterpret_cast<ushort4*>(olo + (size_t)node * D)[lane] = ll;
    } else {
        reinterpret_cast<float4*>(outf + (size_t)node * D)[lane] = acc;
    }
}

// ---------------- mean-pool: 8 chunks per graph, atomic accumulate ----------------
__global__ __launch_bounds__(256) void pool_kernel(const float* __restrict__ h,
                                                   const int* __restrict__ batch,
                                                   float* __restrict__ pooled) {
    int g = blockIdx.x >> 3;
    int c = blockIdx.x & 7;
    int tid = threadIdx.x, w = tid >> 6, lane = tid & 63;
    int lo = 0, hi = N_NODES;
    while (lo < hi) { int m = (lo + hi) >> 1; if (batch[m] < g) lo = m + 1; else hi = m; }
    int start = lo;
    hi = N_NODES;
    while (lo < hi) { int m = (lo + hi) >> 1; if (batch[m] <= g) lo = m + 1; else hi = m; }
    int end = lo;
    float4 acc = make_float4(0.f, 0.f, 0.f, 0.f);
    for (int nd = start + c + 8 * w; nd < end; nd += 32) {
        float4 v = reinterpret_cast<const float4*>(h + (size_t)nd * D)[lane];
        acc.x += v.x; acc.y += v.y; acc.z += v.z; acc.w += v.w;
    }
    float* pg = pooled + g * D + (lane << 2);
    atomicAdd(pg + 0, acc.x);
    atomicAdd(pg + 1, acc.y);
    atomicAdd(pg + 2, acc.z);
    atomicAdd(pg + 3, acc.w);
}

// ---------------- head ----------------
__global__ void final_kernel(const float* __restrict__ pooled, const int* __restrict__ batch,
                             const float* __restrict__ lw, const float* __restrict__ lb,
                             float* __restrict__ out) {
    int g = blockIdx.x;
    int j = threadIdx.x;
    __shared__ float p[D];
    int lo = 0, hi = N_NODES;
    while (lo < hi) { int m = (lo + hi) >> 1; if (batch[m] < g) lo = m + 1; else hi = m; }
    int start = lo;
    hi = N_NODES;
    while (lo < hi) { int m = (lo + hi) >> 1; if (batch[m] <= g) lo = m + 1; else hi = m; }
    int cntg = lo - start;
    float inv = 1.f / (float)(cntg > 0 ? cntg : 1);
    p[j] = pooled[g * D + j] * inv;
    p[j + 128] = pooled[g * D + j + 128] * inv;
    __syncthreads();
    float acc = lb[j];
    for (int k = 0; k < D; ++k) acc = fmaf(p[k], lw[k * N_TASKS + j], acc);
    out[g * N_TASKS + j] = acc;
}

extern "C" void kernel_launch(void* const* d_in, const int* in_sizes, int n_in,
                              void* d_out, int out_size, void* d_ws, size_t ws_size,
                              hipStream_t stream) {
    const float* x   = (const float*)d_in[0];
    const int*   ei  = (const int*)d_in[1];
    const int*   bat = (const int*)d_in[2];
    const float* W1  = (const float*)d_in[3];
    const float* b1  = (const float*)d_in[4];
    const float* W2  = (const float*)d_in[5];
    const float* b2  = (const float*)d_in[6];
    const float* W3  = (const float*)d_in[7];
    const float* b3  = (const float*)d_in[8];
    const float* lw  = (const float*)d_in[9];
    const float* lb  = (const float*)d_in[10];
    float* out = (float*)d_out;

    const int* src = ei;
    const int* dst = ei + N_EDGES;

    char* ws = (char*)d_ws;
    float*          hC      = (float*)         (ws + 0);          // 10,240,000
    float*          hA      = (float*)         (ws + 10240000);   // 10,240,000
    unsigned short* Ah      = (unsigned short*)(ws + 20480000);   //  5,120,000
    unsigned short* Al      = (unsigned short*)(ws + 25600000);   //  5,120,000
    unsigned short* Wth     = (unsigned short*)(ws + 30720000);   //    393,216
    unsigned short* Wtl     = (unsigned short*)(ws + 31113216);   //    393,216
    float*          pooled  = (float*)         (ws + 31506432);   //    131,072
    float*          isd     = (float*)         (ws + 31637504);   //     40,000
    int*            cnt     = (int*)           (ws + 31677504);   //     40,000
    int*            rowptr  = (int*)           (ws + 31717504);   //     40,016
    int2*           edat    = (int2*)          (ws + 31757520);   //  2,560,000
    int*            histbuf = (int*)           (ws + 34317520);   // 10,240,000 (~44.6 MB)

    // CSR build (atomic-free) + weight/x split (once per call)
    init_kernel<<<128, 256, 0, stream>>>(pooled);
    histp_kernel<<<CSR_BLOCKS, 256, 0, stream>>>(dst, histbuf);
    merge_kernel<<<(N_NODES + 255) / 256, 256, 0, stream>>>(histbuf, cnt);
    scan_kernel<<<1, 256, 0, stream>>>(cnt, rowptr, isd);
    scatter_kernel<<<CSR_BLOCKS, 256, 0, stream>>>(src, dst, rowptr, histbuf, isd, edat);
    wsplit_kernel<<<3 * 64, 256, 0, stream>>>(W1, W2, W3, Wth, Wtl);
    split_kernel<<<(N_NODES * D / 4 + 255) / 256, 256, 0, stream>>>(x, Ah, Al);

    dim3 mmgrid((N_NODES + 63) / 64, D / 64);   // 157 x 4
    const int AGG_BLOCKS = N_NODES / 4;         // 2500

    // Layer 1
    mm_kernel<<<mmgrid, 256, 0, stream>>>(Ah, Al, Wth, Wtl, hC);
    agg_kernel<1><<<AGG_BLOCKS, 256, 0, stream>>>(hC, rowptr, edat, isd, b1, nullptr, Ah, Al);
    // Layer 2
    mm_kernel<<<mmgrid, 256, 0, stream>>>(Ah, Al, Wth + D * D, Wtl + D * D, hC);
    agg_kernel<1><<<AGG_BLOCKS, 256, 0, stream>>>(hC, rowptr, edat, isd, b2, nullptr, Ah, Al);
    // Layer 3
    mm_kernel<<<mmgrid, 256, 0, stream>>>(Ah, Al, Wth + 2 * D * D, Wtl + 2 * D * D, hC);
    agg_kernel<0><<<AGG_BLOCKS, 256, 0, stream>>>(hC, rowptr, edat, isd, b3, hA, nullptr, nullptr);

    // Pool + head
    pool_kernel<<<N_GRAPHS * 8, 256, 0, stream>>>(hA, bat, pooled);
    final_kernel<<<N_GRAPHS, 128, 0, stream>>>(pooled, bat, lw, lb, out);
}

// Round 6
// 207.575 us; speedup vs baseline: 2.3588x; 1.1611x over previous
//
#include <hip/hip_runtime.h>

#define N_NODES  10000
#define N_EDGES  320000
#define D        256
#define N_TASKS  128
#define N_GRAPHS 128

#define CSR_BLOCKS 256
#define EPB (N_EDGES / CSR_BLOCKS)   // 1250 edges per block

typedef __attribute__((ext_vector_type(8))) short short8;
typedef __attribute__((ext_vector_type(4))) float floatx4;

__device__ __forceinline__ unsigned short f2bf(float f) {
    unsigned u = __float_as_uint(f);
    u += 0x7FFF + ((u >> 16) & 1);   // RNE
    return (unsigned short)(u >> 16);
}
__device__ __forceinline__ float bf2f(unsigned short h) {
    return __uint_as_float(((unsigned)h) << 16);
}

// ---------------- CSR build, atomic-free (LDS-privatized counting sort) --------

// Pass 1: per-block LDS histogram of dst; per-edge rank saved; flush to ushort histbuf.
__global__ __launch_bounds__(256) void histp_kernel(const int* __restrict__ dst,
                                                    unsigned short* __restrict__ histbuf,
                                                    unsigned short* __restrict__ rank) {
    __shared__ int h[N_NODES];   // 40 KB
    int b = blockIdx.x, t = threadIdx.x;
    for (int i = t; i < N_NODES; i += 256) h[i] = 0;
    __syncthreads();
    int e0 = b * EPB;
    for (int i = t; i < EPB; i += 256) {
        int e = e0 + i;
        int r = atomicAdd(&h[dst[e]], 1);
        rank[e] = (unsigned short)r;
    }
    __syncthreads();
    unsigned short* outp = histbuf + (size_t)b * N_NODES;
    for (int i = t; i < N_NODES; i += 256) outp[i] = (unsigned short)h[i];
}

// Pass 2: per node, running sum over 256 block-rows -> exclusive per-block
// prefixes (in place, ushort) + total count (+1 self-loop).
__global__ __launch_bounds__(256) void merge_kernel(unsigned short* __restrict__ histbuf,
                                                    int* __restrict__ cnt) {
    int n = blockIdx.x * 256 + threadIdx.x;
    if (n >= N_NODES) return;
    int run = 0;
#pragma unroll 1
    for (int b = 0; b < CSR_BLOCKS; b += 8) {
        int v0 = histbuf[(size_t)(b + 0) * N_NODES + n];
        int v1 = histbuf[(size_t)(b + 1) * N_NODES + n];
        int v2 = histbuf[(size_t)(b + 2) * N_NODES + n];
        int v3 = histbuf[(size_t)(b + 3) * N_NODES + n];
        int v4 = histbuf[(size_t)(b + 4) * N_NODES + n];
        int v5 = histbuf[(size_t)(b + 5) * N_NODES + n];
        int v6 = histbuf[(size_t)(b + 6) * N_NODES + n];
        int v7 = histbuf[(size_t)(b + 7) * N_NODES + n];
        histbuf[(size_t)(b + 0) * N_NODES + n] = (unsigned short)run; run += v0;
        histbuf[(size_t)(b + 1) * N_NODES + n] = (unsigned short)run; run += v1;
        histbuf[(size_t)(b + 2) * N_NODES + n] = (unsigned short)run; run += v2;
        histbuf[(size_t)(b + 3) * N_NODES + n] = (unsigned short)run; run += v3;
        histbuf[(size_t)(b + 4) * N_NODES + n] = (unsigned short)run; run += v4;
        histbuf[(size_t)(b + 5) * N_NODES + n] = (unsigned short)run; run += v5;
        histbuf[(size_t)(b + 6) * N_NODES + n] = (unsigned short)run; run += v6;
        histbuf[(size_t)(b + 7) * N_NODES + n] = (unsigned short)run; run += v7;
    }
    cnt[n] = run + 1;   // +1: self-loop
}

// Pass 3: single-block scan of (cnt-1) -> rowptr; isd = rsqrt(cnt).
__global__ __launch_bounds__(256) void scan_kernel(const int* __restrict__ cnt,
                                                   int* __restrict__ rowptr,
                                                   float* __restrict__ isd) {
    __shared__ int scnt[10240];
    __shared__ int part[256];
    const int CH = 40;
    int t = threadIdx.x;
    for (int i = t; i < 2500; i += 256) ((int4*)scnt)[i] = ((const int4*)cnt)[i];  // 10000 ints
    for (int i = 10000 + t; i < 10240; i += 256) scnt[i] = 1;
    __syncthreads();
    int base = t * CH;
    int s = 0;
#pragma unroll 8
    for (int i = 0; i < CH; ++i) s += scnt[base + i] - 1;
    part[t] = s;
    __syncthreads();
    for (int off = 1; off < 256; off <<= 1) {
        int v = (t >= off) ? part[t - off] : 0;
        __syncthreads();
        part[t] += v;
        __syncthreads();
    }
    int run = (t == 0) ? 0 : part[t - 1];
    for (int i = 0; i < CH; ++i) {
        int idx = base + i;
        if (idx < N_NODES) {
            rowptr[idx] = run;
            int c = scnt[idx];
            run += c - 1;
            isd[idx] = rsqrtf((float)c);
        }
    }
    if (t == 255) rowptr[N_NODES] = run;
}

// Pass 4: pure-stream scatter; position = rowptr + block prefix + saved rank.
__global__ __launch_bounds__(256) void scatter_kernel(const int* __restrict__ src,
                                                      const int* __restrict__ dst,
                                                      const unsigned short* __restrict__ rank,
                                                      const int* __restrict__ rowptr,
                                                      const unsigned short* __restrict__ histbuf,
                                                      const float* __restrict__ isd,
                                                      int2* __restrict__ edat) {
    int e = blockIdx.x * 256 + threadIdx.x;
    if (e >= N_EDGES) return;
    int b = e / EPB;
    int s = src[e], d = dst[e];
    int pos = rowptr[d] + (int)histbuf[(size_t)b * N_NODES + d] + (int)rank[e];
    edat[pos] = make_int2(s, __float_as_int(isd[s] * isd[d]));
}

// ---------------- split f32 -> bf16 hi/lo planes ----------------

__global__ __launch_bounds__(256) void split_kernel(const float* __restrict__ in,
                                                    unsigned short* __restrict__ hi,
                                                    unsigned short* __restrict__ lo) {
    int i = blockIdx.x * blockDim.x + threadIdx.x;  // over N_NODES*D/4
    if (i >= N_NODES * D / 4) return;
    float4 v = reinterpret_cast<const float4*>(in)[i];
    ushort4 h, l;
    h.x = f2bf(v.x); l.x = f2bf(v.x - bf2f(h.x));
    h.y = f2bf(v.y); l.y = f2bf(v.y - bf2f(h.y));
    h.z = f2bf(v.z); l.z = f2bf(v.z - bf2f(h.z));
    h.w = f2bf(v.w); l.w = f2bf(v.w - bf2f(h.w));
    reinterpret_cast<ushort4*>(hi)[i] = h;
    reinterpret_cast<ushort4*>(lo)[i] = l;
}

// W[k][n] f32 -> Wt_hi/lo[n][k] bf16 (transposed so mm's b-frag is contiguous)
__global__ __launch_bounds__(256) void wsplit_kernel(const float* __restrict__ W1,
                                                     const float* __restrict__ W2,
                                                     const float* __restrict__ W3,
                                                     unsigned short* __restrict__ wth,
                                                     unsigned short* __restrict__ wtl) {
    __shared__ float t[32][33];
    int b = blockIdx.x;                 // 3*64 blocks
    int w = b >> 6, tile = b & 63;
    int kt = (tile >> 3) << 5, nt = (tile & 7) << 5;
    const float* W = (w == 0) ? W1 : (w == 1) ? W2 : W3;
    int tid = threadIdx.x, r = tid >> 5, c = tid & 31;
#pragma unroll
    for (int i = 0; i < 4; ++i)
        t[r + 8 * i][c] = W[(size_t)(kt + r + 8 * i) * D + nt + c];
    __syncthreads();
    unsigned short* oh = wth + w * D * D;
    unsigned short* ol = wtl + w * D * D;
#pragma unroll
    for (int i = 0; i < 4; ++i) {
        float v = t[c][r + 8 * i];      // = W[kt+c][nt+r+8i]
        unsigned short hv = f2bf(v);
        oh[(size_t)(nt + r + 8 * i) * D + kt + c] = hv;
        ol[(size_t)(nt + r + 8 * i) * D + kt + c] = f2bf(v - bf2f(hv));
    }
}

// ---------------- MFMA matmul: C[N,256] = (Ah+Al) @ (Wh+Wl), 3-plane product ----
__global__ __launch_bounds__(256) void mm_kernel(const unsigned short* __restrict__ Ah,
                                                 const unsigned short* __restrict__ Al,
                                                 const unsigned short* __restrict__ Wh,
                                                 const unsigned short* __restrict__ Wl,
                                                 float* __restrict__ C) {
    __shared__ unsigned short sAh[64][40], sAl[64][40], sWh[64][40], sWl[64][40];
    int tid = threadIdx.x;
    int lane = tid & 63, wid = tid >> 6;
    int wr = wid >> 1, wc = wid & 1;
    int row0 = blockIdx.x << 6;
    int n0 = blockIdx.y << 6;

    int sr = tid >> 2;
    int sk = (tid & 3) << 3;
    int arow = row0 + sr; if (arow >= N_NODES) arow = N_NODES - 1;
    const unsigned short* pAh = Ah + (size_t)arow * D + sk;
    const unsigned short* pAl = Al + (size_t)arow * D + sk;
    const unsigned short* pWh = Wh + (size_t)(n0 + sr) * D + sk;
    const unsigned short* pWl = Wl + (size_t)(n0 + sr) * D + sk;

    uint4 rAh = *(const uint4*)pAh;
    uint4 rAl = *(const uint4*)pAl;
    uint4 rWh = *(const uint4*)pWh;
    uint4 rWl = *(const uint4*)pWl;

    int fr = lane & 15;
    int fk = (lane >> 4) << 3;

    floatx4 acc00 = {0.f, 0.f, 0.f, 0.f};
    floatx4 acc01 = acc00, acc10 = acc00, acc11 = acc00;

#pragma unroll 1
    for (int step = 0; step < D / 32; ++step) {
        *(uint4*)&sAh[sr][sk] = rAh;
        *(uint4*)&sAl[sr][sk] = rAl;
        *(uint4*)&sWh[sr][sk] = rWh;
        *(uint4*)&sWl[sr][sk] = rWl;
        __syncthreads();
        if (step < D / 32 - 1) {
            rAh = *(const uint4*)(pAh + (step + 1) * 32);
            rAl = *(const uint4*)(pAl + (step + 1) * 32);
            rWh = *(const uint4*)(pWh + (step + 1) * 32);
            rWl = *(const uint4*)(pWl + (step + 1) * 32);
        }
        short8 ah0 = *(const short8*)&sAh[(wr << 5) + fr][fk];
        short8 ah1 = *(const short8*)&sAh[(wr << 5) + 16 + fr][fk];
        short8 al0 = *(const short8*)&sAl[(wr << 5) + fr][fk];
        short8 al1 = *(const short8*)&sAl[(wr << 5) + 16 + fr][fk];
        short8 bh0 = *(const short8*)&sWh[(wc << 5) + fr][fk];
        short8 bh1 = *(const short8*)&sWh[(wc << 5) + 16 + fr][fk];
        short8 bl0 = *(const short8*)&sWl[(wc << 5) + fr][fk];
        short8 bl1 = *(const short8*)&sWl[(wc << 5) + 16 + fr][fk];
        acc00 = __builtin_amdgcn_mfma_f32_16x16x32_bf16(ah0, bh0, acc00, 0, 0, 0);
        acc00 = __builtin_amdgcn_mfma_f32_16x16x32_bf16(ah0, bl0, acc00, 0, 0, 0);
        acc00 = __builtin_amdgcn_mfma_f32_16x16x32_bf16(al0, bh0, acc00, 0, 0, 0);
        acc01 = __builtin_amdgcn_mfma_f32_16x16x32_bf16(ah0, bh1, acc01, 0, 0, 0);
        acc01 = __builtin_amdgcn_mfma_f32_16x16x32_bf16(ah0, bl1, acc01, 0, 0, 0);
        acc01 = __builtin_amdgcn_mfma_f32_16x16x32_bf16(al0, bh1, acc01, 0, 0, 0);
        acc10 = __builtin_amdgcn_mfma_f32_16x16x32_bf16(ah1, bh0, acc10, 0, 0, 0);
        acc10 = __builtin_amdgcn_mfma_f32_16x16x32_bf16(ah1, bl0, acc10, 0, 0, 0);
        acc10 = __builtin_amdgcn_mfma_f32_16x16x32_bf16(al1, bh0, acc10, 0, 0, 0);
        acc11 = __builtin_amdgcn_mfma_f32_16x16x32_bf16(ah1, bh1, acc11, 0, 0, 0);
        acc11 = __builtin_amdgcn_mfma_f32_16x16x32_bf16(ah1, bl1, acc11, 0, 0, 0);
        acc11 = __builtin_amdgcn_mfma_f32_16x16x32_bf16(al1, bh1, acc11, 0, 0, 0);
        __syncthreads();
    }

    int crow = (lane >> 4) << 2;
    int colbase = n0 + (wc << 5) + fr;
#pragma unroll
    for (int r = 0; r < 4; ++r) {
        int gr0 = row0 + (wr << 5) + crow + r;
        if (gr0 < N_NODES) {
            C[(size_t)gr0 * D + colbase]      = acc00[r];
            C[(size_t)gr0 * D + colbase + 16] = acc01[r];
        }
        int gr1 = gr0 + 16;
        if (gr1 < N_NODES) {
            C[(size_t)gr1 * D + colbase]      = acc10[r];
            C[(size_t)gr1 * D + colbase + 16] = acc11[r];
        }
    }
}

// ---------------- aggregation: 1 node/block, 4 waves split the edge list --------
// Each wave lane-loads its edge chunk (coalesced int2), shuffle-broadcasts
// {src,w}, gathers 8 rows at a time; LDS combine across the 4 waves.
template <int SPLIT>
__global__ __launch_bounds__(256) void agg_kernel(const float* __restrict__ h,
                                                  const int* __restrict__ rowptr,
                                                  const int2* __restrict__ edat,
                                                  const float* __restrict__ isd,
                                                  const float* __restrict__ bias,
                                                  float* __restrict__ outf,
                                                  unsigned short* __restrict__ ohi,
                                                  unsigned short* __restrict__ olo) {
    __shared__ float part[4][D];
    int node = blockIdx.x;
    int tid = threadIdx.x;
    int w = tid >> 6, lane = tid & 63;
    int e0 = rowptr[node], e1 = rowptr[node + 1];
    int deg = e1 - e0;
    float4 acc = make_float4(0.f, 0.f, 0.f, 0.f);
    if (w == 0) {   // self-loop term
        float isd_i = isd[node];
        float selfn = isd_i * isd_i;
        float4 a = reinterpret_cast<const float4*>(h + (size_t)node * D)[lane];
        acc = make_float4(a.x * selfn, a.y * selfn, a.z * selfn, a.w * selfn);
    }
    int c = (deg + 3) >> 2;
    int js = w * c;
    int je = min(js + c, deg);
    for (int base = js; base < je; base += 64) {
        int n = je - base; if (n > 64) n = 64;
        int2 ed = edat[e0 + base + ((lane < n) ? lane : 0)];
        int j = 0;
        for (; j + 8 <= n; j += 8) {
            int s0 = __shfl(ed.x, j + 0); float w0 = __int_as_float(__shfl(ed.y, j + 0));
            int s1 = __shfl(ed.x, j + 1); float w1 = __int_as_float(__shfl(ed.y, j + 1));
            int s2 = __shfl(ed.x, j + 2); float w2 = __int_as_float(__shfl(ed.y, j + 2));
            int s3 = __shfl(ed.x, j + 3); float w3 = __int_as_float(__shfl(ed.y, j + 3));
            int s4 = __shfl(ed.x, j + 4); float w4 = __int_as_float(__shfl(ed.y, j + 4));
            int s5 = __shfl(ed.x, j + 5); float w5 = __int_as_float(__shfl(ed.y, j + 5));
            int s6 = __shfl(ed.x, j + 6); float w6 = __int_as_float(__shfl(ed.y, j + 6));
            int s7 = __shfl(ed.x, j + 7); float w7 = __int_as_float(__shfl(ed.y, j + 7));
            float4 v0 = reinterpret_cast<const float4*>(h + (size_t)s0 * D)[lane];
            float4 v1 = reinterpret_cast<const float4*>(h + (size_t)s1 * D)[lane];
            float4 v2 = reinterpret_cast<const float4*>(h + (size_t)s2 * D)[lane];
            float4 v3 = reinterpret_cast<const float4*>(h + (size_t)s3 * D)[lane];
            float4 v4 = reinterpret_cast<const float4*>(h + (size_t)s4 * D)[lane];
            float4 v5 = reinterpret_cast<const float4*>(h + (size_t)s5 * D)[lane];
            float4 v6 = reinterpret_cast<const float4*>(h + (size_t)s6 * D)[lane];
            float4 v7 = reinterpret_cast<const float4*>(h + (size_t)s7 * D)[lane];
            acc.x = fmaf(v0.x, w0, acc.x); acc.y = fmaf(v0.y, w0, acc.y);
            acc.z = fmaf(v0.z, w0, acc.z); acc.w = fmaf(v0.w, w0, acc.w);
            acc.x = fmaf(v1.x, w1, acc.x); acc.y = fmaf(v1.y, w1, acc.y);
            acc.z = fmaf(v1.z, w1, acc.z); acc.w = fmaf(v1.w, w1, acc.w);
            acc.x = fmaf(v2.x, w2, acc.x); acc.y = fmaf(v2.y, w2, acc.y);
            acc.z = fmaf(v2.z, w2, acc.z); acc.w = fmaf(v2.w, w2, acc.w);
            acc.x = fmaf(v3.x, w3, acc.x); acc.y = fmaf(v3.y, w3, acc.y);
            acc.z = fmaf(v3.z, w3, acc.z); acc.w = fmaf(v3.w, w3, acc.w);
            acc.x = fmaf(v4.x, w4, acc.x); acc.y = fmaf(v4.y, w4, acc.y);
            acc.z = fmaf(v4.z, w4, acc.z); acc.w = fmaf(v4.w, w4, acc.w);
            acc.x = fmaf(v5.x, w5, acc.x); acc.y = fmaf(v5.y, w5, acc.y);
            acc.z = fmaf(v5.z, w5, acc.z); acc.w = fmaf(v5.w, w5, acc.w);
            acc.x = fmaf(v6.x, w6, acc.x); acc.y = fmaf(v6.y, w6, acc.y);
            acc.z = fmaf(v6.z, w6, acc.z); acc.w = fmaf(v6.w, w6, acc.w);
            acc.x = fmaf(v7.x, w7, acc.x); acc.y = fmaf(v7.y, w7, acc.y);
            acc.z = fmaf(v7.z, w7, acc.z); acc.w = fmaf(v7.w, w7, acc.w);
        }
        for (; j < n; ++j) {
            int s = __shfl(ed.x, j);
            float wt = __int_as_float(__shfl(ed.y, j));
            float4 v = reinterpret_cast<const float4*>(h + (size_t)s * D)[lane];
            acc.x = fmaf(v.x, wt, acc.x); acc.y = fmaf(v.y, wt, acc.y);
            acc.z = fmaf(v.z, wt, acc.z); acc.w = fmaf(v.w, wt, acc.w);
        }
    }
    reinterpret_cast<float4*>(part[w])[lane] = acc;
    __syncthreads();
    int t = tid;   // 256 threads = 256 dims
    float v = part[0][t] + part[1][t] + part[2][t] + part[3][t] + bias[t];
    v = fmaxf(v, 0.f);
    if (SPLIT) {
        unsigned short hv = f2bf(v);
        ohi[(size_t)node * D + t] = hv;
        olo[(size_t)node * D + t] = f2bf(v - bf2f(hv));
    } else {
        outf[(size_t)node * D + t] = v;
    }
}

// ---------------- fused mean-pool + head ----------------
__global__ __launch_bounds__(256) void poolfinal_kernel(const float* __restrict__ h,
                                                        const int* __restrict__ batch,
                                                        const float* __restrict__ lw,
                                                        const float* __restrict__ lb,
                                                        float* __restrict__ out) {
    __shared__ float part[4][D];
    __shared__ float p[D];
    int g = blockIdx.x;
    int tid = threadIdx.x, w = tid >> 6, lane = tid & 63;
    int lo = 0, hi = N_NODES;
    while (lo < hi) { int m = (lo + hi) >> 1; if (batch[m] < g) lo = m + 1; else hi = m; }
    int start = lo;
    hi = N_NODES;
    while (lo < hi) { int m = (lo + hi) >> 1; if (batch[m] <= g) lo = m + 1; else hi = m; }
    int end = lo;
    float4 acc = make_float4(0.f, 0.f, 0.f, 0.f);
    for (int nd = start + w; nd < end; nd += 4) {
        float4 v = reinterpret_cast<const float4*>(h + (size_t)nd * D)[lane];
        acc.x += v.x; acc.y += v.y; acc.z += v.z; acc.w += v.w;
    }
    reinterpret_cast<float4*>(part[w])[lane] = acc;
    __syncthreads();
    float invc = 1.f / (float)((end > start) ? (end - start) : 1);
    p[tid] = (part[0][tid] + part[1][tid] + part[2][tid] + part[3][tid]) * invc;
    __syncthreads();
    if (tid < N_TASKS) {
        float a = lb[tid];
        for (int k = 0; k < D; ++k) a = fmaf(p[k], lw[k * N_TASKS + tid], a);
        out[g * N_TASKS + tid] = a;
    }
}

extern "C" void kernel_launch(void* const* d_in, const int* in_sizes, int n_in,
                              void* d_out, int out_size, void* d_ws, size_t ws_size,
                              hipStream_t stream) {
    const float* x   = (const float*)d_in[0];
    const int*   ei  = (const int*)d_in[1];
    const int*   bat = (const int*)d_in[2];
    const float* W1  = (const float*)d_in[3];
    const float* b1  = (const float*)d_in[4];
    const float* W2  = (const float*)d_in[5];
    const float* b2  = (const float*)d_in[6];
    const float* W3  = (const float*)d_in[7];
    const float* b3  = (const float*)d_in[8];
    const float* lw  = (const float*)d_in[9];
    const float* lb  = (const float*)d_in[10];
    float* out = (float*)d_out;

    const int* src = ei;
    const int* dst = ei + N_EDGES;

    char* ws = (char*)d_ws;
    float*          hC      = (float*)         (ws + 0);          // 10,240,000
    float*          hA      = (float*)         (ws + 10240000);   // 10,240,000
    unsigned short* Ah      = (unsigned short*)(ws + 20480000);   //  5,120,000
    unsigned short* Al      = (unsigned short*)(ws + 25600000);   //  5,120,000
    unsigned short* Wth     = (unsigned short*)(ws + 30720000);   //    393,216
    unsigned short* Wtl     = (unsigned short*)(ws + 31113216);   //    393,216
    float*          isd     = (float*)         (ws + 31506432);   //     40,000
    int*            cnt     = (int*)           (ws + 31546432);   //     40,000
    int*            rowptr  = (int*)           (ws + 31586432);   //     40,016
    int2*           edat    = (int2*)          (ws + 31626448);   //  2,560,000
    unsigned short* histbuf = (unsigned short*)(ws + 34186448);   //  5,120,000
    unsigned short* rank    = (unsigned short*)(ws + 39306448);   //    640,000  (~39.9 MB)

    // CSR build (atomic-free) + weight/x split (once per call)
    histp_kernel<<<CSR_BLOCKS, 256, 0, stream>>>(dst, histbuf, rank);
    merge_kernel<<<(N_NODES + 255) / 256, 256, 0, stream>>>(histbuf, cnt);
    scan_kernel<<<1, 256, 0, stream>>>(cnt, rowptr, isd);
    scatter_kernel<<<(N_EDGES + 255) / 256, 256, 0, stream>>>(src, dst, rank, rowptr,
                                                              histbuf, isd, edat);
    wsplit_kernel<<<3 * 64, 256, 0, stream>>>(W1, W2, W3, Wth, Wtl);
    split_kernel<<<(N_NODES * D / 4 + 255) / 256, 256, 0, stream>>>(x, Ah, Al);

    dim3 mmgrid((N_NODES + 63) / 64, D / 64);   // 157 x 4

    // Layer 1
    mm_kernel<<<mmgrid, 256, 0, stream>>>(Ah, Al, Wth, Wtl, hC);
    agg_kernel<1><<<N_NODES, 256, 0, stream>>>(hC, rowptr, edat, isd, b1, nullptr, Ah, Al);
    // Layer 2
    mm_kernel<<<mmgrid, 256, 0, stream>>>(Ah, Al, Wth + D * D, Wtl + D * D, hC);
    agg_kernel<1><<<N_NODES, 256, 0, stream>>>(hC, rowptr, edat, isd, b2, nullptr, Ah, Al);
    // Layer 3
    mm_kernel<<<mmgrid, 256, 0, stream>>>(Ah, Al, Wth + 2 * D * D, Wtl + 2 * D * D, hC);
    agg_kernel<0><<<N_NODES, 256, 0, stream>>>(hC, rowptr, edat, isd, b3, hA, nullptr, nullptr);

    // Fused pool + head
    poolfinal_kernel<<<N_GRAPHS, 256, 0, stream>>>(hA, bat, lw, lb, out);
}

// Round 7
// 165.238 us; speedup vs baseline: 2.9632x; 1.2562x over previous
//
#include <hip/hip_runtime.h>

#define N_NODES  10000
#define N_EDGES  320000
#define D        256
#define N_TASKS  128
#define N_GRAPHS 128

#define CSR_BLOCKS 128
#define EPB (N_EDGES / CSR_BLOCKS)   // 2500 edges per block

typedef __attribute__((ext_vector_type(8))) short short8;
typedef __attribute__((ext_vector_type(4))) float floatx4;

__device__ __forceinline__ unsigned short f2bf(float f) {
    unsigned u = __float_as_uint(f);
    u += 0x7FFF + ((u >> 16) & 1);   // RNE
    return (unsigned short)(u >> 16);
}
__device__ __forceinline__ float bf2f(unsigned short h) {
    return __uint_as_float(((unsigned)h) << 16);
}
__device__ __forceinline__ unsigned short f2h(float f) {
    _Float16 h = (_Float16)f;
    return *(unsigned short*)&h;
}
__device__ __forceinline__ float h2f(unsigned short u) {
    _Float16 h = *(_Float16*)&u;
    return (float)h;
}

// ---------------- CSR build, atomic-free (LDS-privatized counting sort) --------

// Pass 1: per-block LDS histogram of dst; per-edge rank saved; flush to ushort histbuf.
__global__ __launch_bounds__(256) void histp_kernel(const int* __restrict__ dst,
                                                    unsigned short* __restrict__ histbuf,
                                                    unsigned short* __restrict__ rank) {
    __shared__ int h[N_NODES];   // 40 KB
    int b = blockIdx.x, t = threadIdx.x;
    for (int i = t; i < N_NODES; i += 256) h[i] = 0;
    __syncthreads();
    int e0 = b * EPB;
    for (int i = t; i < EPB; i += 256) {
        int e = e0 + i;
        int r = atomicAdd(&h[dst[e]], 1);
        rank[e] = (unsigned short)r;
    }
    __syncthreads();
    unsigned short* outp = histbuf + (size_t)b * N_NODES;
    for (int i = t; i < N_NODES; i += 256) outp[i] = (unsigned short)h[i];
}

// Pass 2: per node, running sum over block-rows -> exclusive per-block prefixes
// (in place, ushort) + total count (+1 self-loop).
__global__ __launch_bounds__(256) void merge_kernel(unsigned short* __restrict__ histbuf,
                                                    int* __restrict__ cnt) {
    int n = blockIdx.x * 256 + threadIdx.x;
    if (n >= N_NODES) return;
    int run = 0;
#pragma unroll 1
    for (int b = 0; b < CSR_BLOCKS; b += 8) {
        int v0 = histbuf[(size_t)(b + 0) * N_NODES + n];
        int v1 = histbuf[(size_t)(b + 1) * N_NODES + n];
        int v2 = histbuf[(size_t)(b + 2) * N_NODES + n];
        int v3 = histbuf[(size_t)(b + 3) * N_NODES + n];
        int v4 = histbuf[(size_t)(b + 4) * N_NODES + n];
        int v5 = histbuf[(size_t)(b + 5) * N_NODES + n];
        int v6 = histbuf[(size_t)(b + 6) * N_NODES + n];
        int v7 = histbuf[(size_t)(b + 7) * N_NODES + n];
        histbuf[(size_t)(b + 0) * N_NODES + n] = (unsigned short)run; run += v0;
        histbuf[(size_t)(b + 1) * N_NODES + n] = (unsigned short)run; run += v1;
        histbuf[(size_t)(b + 2) * N_NODES + n] = (unsigned short)run; run += v2;
        histbuf[(size_t)(b + 3) * N_NODES + n] = (unsigned short)run; run += v3;
        histbuf[(size_t)(b + 4) * N_NODES + n] = (unsigned short)run; run += v4;
        histbuf[(size_t)(b + 5) * N_NODES + n] = (unsigned short)run; run += v5;
        histbuf[(size_t)(b + 6) * N_NODES + n] = (unsigned short)run; run += v6;
        histbuf[(size_t)(b + 7) * N_NODES + n] = (unsigned short)run; run += v7;
    }
    cnt[n] = run + 1;   // +1: self-loop
}

// Pass 3: single-block scan of (cnt-1) -> rowptr; isd = rsqrt(cnt).
__global__ __launch_bounds__(256) void scan_kernel(const int* __restrict__ cnt,
                                                   int* __restrict__ rowptr,
                                                   float* __restrict__ isd) {
    __shared__ int scnt[10240];
    __shared__ int part[256];
    const int CH = 40;
    int t = threadIdx.x;
    for (int i = t; i < 2500; i += 256) ((int4*)scnt)[i] = ((const int4*)cnt)[i];  // 10000 ints
    for (int i = 10000 + t; i < 10240; i += 256) scnt[i] = 1;
    __syncthreads();
    int base = t * CH;
    int s = 0;
#pragma unroll 8
    for (int i = 0; i < CH; ++i) s += scnt[base + i] - 1;
    part[t] = s;
    __syncthreads();
    for (int off = 1; off < 256; off <<= 1) {
        int v = (t >= off) ? part[t - off] : 0;
        __syncthreads();
        part[t] += v;
        __syncthreads();
    }
    int run = (t == 0) ? 0 : part[t - 1];
    for (int i = 0; i < CH; ++i) {
        int idx = base + i;
        if (idx < N_NODES) {
            rowptr[idx] = run;
            int c = scnt[idx];
            run += c - 1;
            isd[idx] = rsqrtf((float)c);
        }
    }
    if (t == 255) rowptr[N_NODES] = run;
}

// Pass 4: pure-stream scatter; position = rowptr + block prefix + saved rank.
__global__ __launch_bounds__(256) void scatter_kernel(const int* __restrict__ src,
                                                      const int* __restrict__ dst,
                                                      const unsigned short* __restrict__ rank,
                                                      const int* __restrict__ rowptr,
                                                      const unsigned short* __restrict__ histbuf,
                                                      const float* __restrict__ isd,
                                                      int2* __restrict__ edat) {
    int e = blockIdx.x * 256 + threadIdx.x;
    if (e >= N_EDGES) return;
    int b = e / EPB;
    int s = src[e], d = dst[e];
    int pos = rowptr[d] + (int)histbuf[(size_t)b * N_NODES + d] + (int)rank[e];
    edat[pos] = make_int2(s, __float_as_int(isd[s] * isd[d]));
}

// W[k][n] f32 -> Wt_hi/lo[n][k] bf16 (transposed so mm's b-frag is contiguous)
__global__ __launch_bounds__(256) void wsplit_kernel(const float* __restrict__ W1,
                                                     const float* __restrict__ W2,
                                                     const float* __restrict__ W3,
                                                     unsigned short* __restrict__ wth,
                                                     unsigned short* __restrict__ wtl) {
    __shared__ float t[32][33];
    int b = blockIdx.x;                 // 3*64 blocks
    int w = b >> 6, tile = b & 63;
    int kt = (tile >> 3) << 5, nt = (tile & 7) << 5;
    const float* W = (w == 0) ? W1 : (w == 1) ? W2 : W3;
    int tid = threadIdx.x, r = tid >> 5, c = tid & 31;
#pragma unroll
    for (int i = 0; i < 4; ++i)
        t[r + 8 * i][c] = W[(size_t)(kt + r + 8 * i) * D + nt + c];
    __syncthreads();
    unsigned short* oh = wth + w * D * D;
    unsigned short* ol = wtl + w * D * D;
#pragma unroll
    for (int i = 0; i < 4; ++i) {
        float v = t[c][r + 8 * i];      // = W[kt+c][nt+r+8i]
        unsigned short hv = f2bf(v);
        oh[(size_t)(nt + r + 8 * i) * D + kt + c] = hv;
        ol[(size_t)(nt + r + 8 * i) * D + kt + c] = f2bf(v - bf2f(hv));
    }
}

// ---------------- MFMA matmul: C_fp16[N,256] = A_f32 @ (Wh+Wl) -----------------
// A is f32; the bf16 hi/lo split happens in-register during LDS staging.
// 64x64 tile, BK=32, 4 waves 2x2, wave-tile 32x32; output stored as fp16.
__global__ __launch_bounds__(256) void mm_kernel(const float* __restrict__ A,
                                                 const unsigned short* __restrict__ Wh,
                                                 const unsigned short* __restrict__ Wl,
                                                 unsigned short* __restrict__ C) {
    __shared__ unsigned short sAh[64][40], sAl[64][40], sWh[64][40], sWl[64][40];
    int tid = threadIdx.x;
    int lane = tid & 63, wid = tid >> 6;
    int wr = wid >> 1, wc = wid & 1;
    int row0 = blockIdx.x << 6;
    int n0 = blockIdx.y << 6;

    int sr = tid >> 2;              // 0..63 tile row
    int sk = (tid & 3) << 3;        // 0,8,16,24 k elems
    int arow = row0 + sr; if (arow >= N_NODES) arow = N_NODES - 1;  // clamp; stores guarded
    const float* pA = A + (size_t)arow * D + sk;
    const unsigned short* pWh = Wh + (size_t)(n0 + sr) * D + sk;
    const unsigned short* pWl = Wl + (size_t)(n0 + sr) * D + sk;

    float4 ra0 = *(const float4*)pA;
    float4 ra1 = *(const float4*)(pA + 4);
    uint4 rWh = *(const uint4*)pWh;
    uint4 rWl = *(const uint4*)pWl;

    int fr = lane & 15;
    int fk = (lane >> 4) << 3;

    floatx4 acc00 = {0.f, 0.f, 0.f, 0.f};
    floatx4 acc01 = acc00, acc10 = acc00, acc11 = acc00;

#pragma unroll 1
    for (int step = 0; step < D / 32; ++step) {
        // in-register f32 -> bf16 hi/lo split, then stage to LDS
        {
            float vv[8] = {ra0.x, ra0.y, ra0.z, ra0.w, ra1.x, ra1.y, ra1.z, ra1.w};
            union { unsigned short u[8]; uint4 v; } ph, pl;
#pragma unroll
            for (int j = 0; j < 8; ++j) {
                unsigned short hv = f2bf(vv[j]);
                ph.u[j] = hv;
                pl.u[j] = f2bf(vv[j] - bf2f(hv));
            }
            *(uint4*)&sAh[sr][sk] = ph.v;
            *(uint4*)&sAl[sr][sk] = pl.v;
        }
        *(uint4*)&sWh[sr][sk] = rWh;
        *(uint4*)&sWl[sr][sk] = rWl;
        __syncthreads();
        if (step < D / 32 - 1) {    // prefetch next k-slice
            ra0 = *(const float4*)(pA + (step + 1) * 32);
            ra1 = *(const float4*)(pA + (step + 1) * 32 + 4);
            rWh = *(const uint4*)(pWh + (step + 1) * 32);
            rWl = *(const uint4*)(pWl + (step + 1) * 32);
        }
        short8 ah0 = *(const short8*)&sAh[(wr << 5) + fr][fk];
        short8 ah1 = *(const short8*)&sAh[(wr << 5) + 16 + fr][fk];
        short8 al0 = *(const short8*)&sAl[(wr << 5) + fr][fk];
        short8 al1 = *(const short8*)&sAl[(wr << 5) + 16 + fr][fk];
        short8 bh0 = *(const short8*)&sWh[(wc << 5) + fr][fk];
        short8 bh1 = *(const short8*)&sWh[(wc << 5) + 16 + fr][fk];
        short8 bl0 = *(const short8*)&sWl[(wc << 5) + fr][fk];
        short8 bl1 = *(const short8*)&sWl[(wc << 5) + 16 + fr][fk];
        acc00 = __builtin_amdgcn_mfma_f32_16x16x32_bf16(ah0, bh0, acc00, 0, 0, 0);
        acc00 = __builtin_amdgcn_mfma_f32_16x16x32_bf16(ah0, bl0, acc00, 0, 0, 0);
        acc00 = __builtin_amdgcn_mfma_f32_16x16x32_bf16(al0, bh0, acc00, 0, 0, 0);
        acc01 = __builtin_amdgcn_mfma_f32_16x16x32_bf16(ah0, bh1, acc01, 0, 0, 0);
        acc01 = __builtin_amdgcn_mfma_f32_16x16x32_bf16(ah0, bl1, acc01, 0, 0, 0);
        acc01 = __builtin_amdgcn_mfma_f32_16x16x32_bf16(al0, bh1, acc01, 0, 0, 0);
        acc10 = __builtin_amdgcn_mfma_f32_16x16x32_bf16(ah1, bh0, acc10, 0, 0, 0);
        acc10 = __builtin_amdgcn_mfma_f32_16x16x32_bf16(ah1, bl0, acc10, 0, 0, 0);
        acc10 = __builtin_amdgcn_mfma_f32_16x16x32_bf16(al1, bh0, acc10, 0, 0, 0);
        acc11 = __builtin_amdgcn_mfma_f32_16x16x32_bf16(ah1, bh1, acc11, 0, 0, 0);
        acc11 = __builtin_amdgcn_mfma_f32_16x16x32_bf16(ah1, bl1, acc11, 0, 0, 0);
        acc11 = __builtin_amdgcn_mfma_f32_16x16x32_bf16(al1, bh1, acc11, 0, 0, 0);
        __syncthreads();
    }

    // C/D layout: col = lane&15, row = (lane>>4)*4 + reg   [m89-verified]
    int crow = (lane >> 4) << 2;
    int colbase = n0 + (wc << 5) + fr;
#pragma unroll
    for (int r = 0; r < 4; ++r) {
        int gr0 = row0 + (wr << 5) + crow + r;
        if (gr0 < N_NODES) {
            C[(size_t)gr0 * D + colbase]      = f2h(acc00[r]);
            C[(size_t)gr0 * D + colbase + 16] = f2h(acc01[r]);
        }
        int gr1 = gr0 + 16;
        if (gr1 < N_NODES) {
            C[(size_t)gr1 * D + colbase]      = f2h(acc10[r]);
            C[(size_t)gr1 * D + colbase + 16] = f2h(acc11[r]);
        }
    }
}

// ---------------- aggregation: 1 node/block, 4 waves split the edge list --------
// h rows are fp16 (512 B) -> half the gather bytes. Output f32 (mm re-splits).
__global__ __launch_bounds__(256) void agg_kernel(const unsigned short* __restrict__ h,
                                                  const int* __restrict__ rowptr,
                                                  const int2* __restrict__ edat,
                                                  const float* __restrict__ isd,
                                                  const float* __restrict__ bias,
                                                  float* __restrict__ outf) {
    __shared__ float part[4][D];
    int node = blockIdx.x;
    int tid = threadIdx.x;
    int w = tid >> 6, lane = tid & 63;
    int e0 = rowptr[node], e1 = rowptr[node + 1];
    int deg = e1 - e0;
    float4 acc = make_float4(0.f, 0.f, 0.f, 0.f);
    if (w == 0) {   // self-loop term
        float isd_i = isd[node];
        float selfn = isd_i * isd_i;
        ushort4 q = reinterpret_cast<const ushort4*>(h + (size_t)node * D)[lane];
        acc = make_float4(h2f(q.x) * selfn, h2f(q.y) * selfn,
                          h2f(q.z) * selfn, h2f(q.w) * selfn);
    }
    int c = (deg + 3) >> 2;
    int js = w * c;
    int je = min(js + c, deg);
    for (int base = js; base < je; base += 64) {
        int n = je - base; if (n > 64) n = 64;
        int2 ed = edat[e0 + base + ((lane < n) ? lane : 0)];
        int j = 0;
        for (; j + 8 <= n; j += 8) {
            int s0 = __shfl(ed.x, j + 0); float w0 = __int_as_float(__shfl(ed.y, j + 0));
            int s1 = __shfl(ed.x, j + 1); float w1 = __int_as_float(__shfl(ed.y, j + 1));
            int s2 = __shfl(ed.x, j + 2); float w2 = __int_as_float(__shfl(ed.y, j + 2));
            int s3 = __shfl(ed.x, j + 3); float w3 = __int_as_float(__shfl(ed.y, j + 3));
            int s4 = __shfl(ed.x, j + 4); float w4 = __int_as_float(__shfl(ed.y, j + 4));
            int s5 = __shfl(ed.x, j + 5); float w5 = __int_as_float(__shfl(ed.y, j + 5));
            int s6 = __shfl(ed.x, j + 6); float w6 = __int_as_float(__shfl(ed.y, j + 6));
            int s7 = __shfl(ed.x, j + 7); float w7 = __int_as_float(__shfl(ed.y, j + 7));
            ushort4 q0 = reinterpret_cast<const ushort4*>(h + (size_t)s0 * D)[lane];
            ushort4 q1 = reinterpret_cast<const ushort4*>(h + (size_t)s1 * D)[lane];
            ushort4 q2 = reinterpret_cast<const ushort4*>(h + (size_t)s2 * D)[lane];
            ushort4 q3 = reinterpret_cast<const ushort4*>(h + (size_t)s3 * D)[lane];
            ushort4 q4 = reinterpret_cast<const ushort4*>(h + (size_t)s4 * D)[lane];
            ushort4 q5 = reinterpret_cast<const ushort4*>(h + (size_t)s5 * D)[lane];
            ushort4 q6 = reinterpret_cast<const ushort4*>(h + (size_t)s6 * D)[lane];
            ushort4 q7 = reinterpret_cast<const ushort4*>(h + (size_t)s7 * D)[lane];
            acc.x = fmaf(h2f(q0.x), w0, acc.x); acc.y = fmaf(h2f(q0.y), w0, acc.y);
            acc.z = fmaf(h2f(q0.z), w0, acc.z); acc.w = fmaf(h2f(q0.w), w0, acc.w);
            acc.x = fmaf(h2f(q1.x), w1, acc.x); acc.y = fmaf(h2f(q1.y), w1, acc.y);
            acc.z = fmaf(h2f(q1.z), w1, acc.z); acc.w = fmaf(h2f(q1.w), w1, acc.w);
            acc.x = fmaf(h2f(q2.x), w2, acc.x); acc.y = fmaf(h2f(q2.y), w2, acc.y);
            acc.z = fmaf(h2f(q2.z), w2, acc.z); acc.w = fmaf(h2f(q2.w), w2, acc.w);
            acc.x = fmaf(h2f(q3.x), w3, acc.x); acc.y = fmaf(h2f(q3.y), w3, acc.y);
            acc.z = fmaf(h2f(q3.z), w3, acc.z); acc.w = fmaf(h2f(q3.w), w3, acc.w);
            acc.x = fmaf(h2f(q4.x), w4, acc.x); acc.y = fmaf(h2f(q4.y), w4, acc.y);
            acc.z = fmaf(h2f(q4.z), w4, acc.z); acc.w = fmaf(h2f(q4.w), w4, acc.w);
            acc.x = fmaf(h2f(q5.x), w5, acc.x); acc.y = fmaf(h2f(q5.y), w5, acc.y);
            acc.z = fmaf(h2f(q5.z), w5, acc.z); acc.w = fmaf(h2f(q5.w), w5, acc.w);
            acc.x = fmaf(h2f(q6.x), w6, acc.x); acc.y = fmaf(h2f(q6.y), w6, acc.y);
            acc.z = fmaf(h2f(q6.z), w6, acc.z); acc.w = fmaf(h2f(q6.w), w6, acc.w);
            acc.x = fmaf(h2f(q7.x), w7, acc.x); acc.y = fmaf(h2f(q7.y), w7, acc.y);
            acc.z = fmaf(h2f(q7.z), w7, acc.z); acc.w = fmaf(h2f(q7.w), w7, acc.w);
        }
        for (; j < n; ++j) {
            int s = __shfl(ed.x, j);
            float wt = __int_as_float(__shfl(ed.y, j));
            ushort4 q = reinterpret_cast<const ushort4*>(h + (size_t)s * D)[lane];
            acc.x = fmaf(h2f(q.x), wt, acc.x); acc.y = fmaf(h2f(q.y), wt, acc.y);
            acc.z = fmaf(h2f(q.z), wt, acc.z); acc.w = fmaf(h2f(q.w), wt, acc.w);
        }
    }
    reinterpret_cast<float4*>(part[w])[lane] = acc;
    __syncthreads();
    int t = tid;   // 256 threads = 256 dims
    float v = part[0][t] + part[1][t] + part[2][t] + part[3][t] + bias[t];
    outf[(size_t)node * D + t] = fmaxf(v, 0.f);
}

// ---------------- fused mean-pool + head ----------------
__global__ __launch_bounds__(256) void poolfinal_kernel(const float* __restrict__ h,
                                                        const int* __restrict__ batch,
                                                        const float* __restrict__ lw,
                                                        const float* __restrict__ lb,
                                                        float* __restrict__ out) {
    __shared__ float part[4][D];
    __shared__ float p[D];
    int g = blockIdx.x;
    int tid = threadIdx.x, w = tid >> 6, lane = tid & 63;
    int lo = 0, hi = N_NODES;
    while (lo < hi) { int m = (lo + hi) >> 1; if (batch[m] < g) lo = m + 1; else hi = m; }
    int start = lo;
    hi = N_NODES;
    while (lo < hi) { int m = (lo + hi) >> 1; if (batch[m] <= g) lo = m + 1; else hi = m; }
    int end = lo;
    float4 acc = make_float4(0.f, 0.f, 0.f, 0.f);
    for (int nd = start + w; nd < end; nd += 4) {
        float4 v = reinterpret_cast<const float4*>(h + (size_t)nd * D)[lane];
        acc.x += v.x; acc.y += v.y; acc.z += v.z; acc.w += v.w;
    }
    reinterpret_cast<float4*>(part[w])[lane] = acc;
    __syncthreads();
    float invc = 1.f / (float)((end > start) ? (end - start) : 1);
    p[tid] = (part[0][tid] + part[1][tid] + part[2][tid] + part[3][tid]) * invc;
    __syncthreads();
    if (tid < N_TASKS) {
        float a = lb[tid];
        for (int k = 0; k < D; ++k) a = fmaf(p[k], lw[k * N_TASKS + tid], a);
        out[g * N_TASKS + tid] = a;
    }
}

extern "C" void kernel_launch(void* const* d_in, const int* in_sizes, int n_in,
                              void* d_out, int out_size, void* d_ws, size_t ws_size,
                              hipStream_t stream) {
    const float* x   = (const float*)d_in[0];
    const int*   ei  = (const int*)d_in[1];
    const int*   bat = (const int*)d_in[2];
    const float* W1  = (const float*)d_in[3];
    const float* b1  = (const float*)d_in[4];
    const float* W2  = (const float*)d_in[5];
    const float* b2  = (const float*)d_in[6];
    const float* W3  = (const float*)d_in[7];
    const float* b3  = (const float*)d_in[8];
    const float* lw  = (const float*)d_in[9];
    const float* lb  = (const float*)d_in[10];
    float* out = (float*)d_out;

    const int* src = ei;
    const int* dst = ei + N_EDGES;

    char* ws = (char*)d_ws;
    float*          gF      = (float*)         (ws + 0);          // 10,240,000 (f32 agg out)
    unsigned short* hH      = (unsigned short*)(ws + 10240000);   //  5,120,000 (fp16 mm out)
    unsigned short* Wth     = (unsigned short*)(ws + 15360000);   //    393,216
    unsigned short* Wtl     = (unsigned short*)(ws + 15753216);   //    393,216
    float*          isd     = (float*)         (ws + 16146432);   //     40,000
    int*            cnt     = (int*)           (ws + 16186432);   //     40,000
    int*            rowptr  = (int*)           (ws + 16226432);   //     40,016
    int2*           edat    = (int2*)          (ws + 16266448);   //  2,560,000
    unsigned short* histbuf = (unsigned short*)(ws + 18826448);   //  2,560,000
    unsigned short* rank    = (unsigned short*)(ws + 21386448);   //    640,000  (~22 MB)

    // CSR build (atomic-free) + weight split (once per call)
    histp_kernel<<<CSR_BLOCKS, 256, 0, stream>>>(dst, histbuf, rank);
    merge_kernel<<<(N_NODES + 255) / 256, 256, 0, stream>>>(histbuf, cnt);
    scan_kernel<<<1, 256, 0, stream>>>(cnt, rowptr, isd);
    scatter_kernel<<<(N_EDGES + 255) / 256, 256, 0, stream>>>(src, dst, rank, rowptr,
                                                              histbuf, isd, edat);
    wsplit_kernel<<<3 * 64, 256, 0, stream>>>(W1, W2, W3, Wth, Wtl);

    dim3 mmgrid((N_NODES + 63) / 64, D / 64);   // 157 x 4

    // Layer 1
    mm_kernel<<<mmgrid, 256, 0, stream>>>(x, Wth, Wtl, hH);
    agg_kernel<<<N_NODES, 256, 0, stream>>>(hH, rowptr, edat, isd, b1, gF);
    // Layer 2
    mm_kernel<<<mmgrid, 256, 0, stream>>>(gF, Wth + D * D, Wtl + D * D, hH);
    agg_kernel<<<N_NODES, 256, 0, stream>>>(hH, rowptr, edat, isd, b2, gF);
    // Layer 3
    mm_kernel<<<mmgrid, 256, 0, stream>>>(gF, Wth + 2 * D * D, Wtl + 2 * D * D, hH);
    agg_kernel<<<N_NODES, 256, 0, stream>>>(hH, rowptr, edat, isd, b3, gF);

    // Fused pool + head
    poolfinal_kernel<<<N_GRAPHS, 256, 0, stream>>>(gF, bat, lw, lb, out);
}

// Round 8
// 162.053 us; speedup vs baseline: 3.0215x; 1.0197x over previous
//
#include <hip/hip_runtime.h>

#define N_NODES  10000
#define N_EDGES  320000
#define D        256
#define N_TASKS  128
#define N_GRAPHS 128

#define CSR_BLOCKS 128
#define EPB (N_EDGES / CSR_BLOCKS)   // 2500 edges per block

typedef __attribute__((ext_vector_type(8))) _Float16 half8;
typedef __attribute__((ext_vector_type(4))) float floatx4;

__device__ __forceinline__ unsigned short f2h(float f) {
    _Float16 h = (_Float16)f;
    return *(unsigned short*)&h;
}
__device__ __forceinline__ float h2f(unsigned short u) {
    _Float16 h = *(_Float16*)&u;
    return (float)h;
}

// ---------------- CSR build, atomic-free (LDS-privatized counting sort) --------

// Pass 1: per-block LDS histogram of dst; per-edge rank saved; flush to ushort histbuf.
__global__ __launch_bounds__(256) void histp_kernel(const int* __restrict__ dst,
                                                    unsigned short* __restrict__ histbuf,
                                                    unsigned short* __restrict__ rank) {
    __shared__ int h[N_NODES];   // 40 KB
    int b = blockIdx.x, t = threadIdx.x;
    for (int i = t; i < N_NODES; i += 256) h[i] = 0;
    __syncthreads();
    int e0 = b * EPB;
    for (int i = t; i < EPB; i += 256) {
        int e = e0 + i;
        int r = atomicAdd(&h[dst[e]], 1);
        rank[e] = (unsigned short)r;
    }
    __syncthreads();
    unsigned short* outp = histbuf + (size_t)b * N_NODES;
    for (int i = t; i < N_NODES; i += 256) outp[i] = (unsigned short)h[i];
}

// Pass 2: per node, running sum over block-rows -> exclusive per-block prefixes
// (in place, ushort) + total count (+1 self-loop).
__global__ __launch_bounds__(256) void merge_kernel(unsigned short* __restrict__ histbuf,
                                                    int* __restrict__ cnt) {
    int n = blockIdx.x * 256 + threadIdx.x;
    if (n >= N_NODES) return;
    int run = 0;
#pragma unroll 1
    for (int b = 0; b < CSR_BLOCKS; b += 8) {
        int v0 = histbuf[(size_t)(b + 0) * N_NODES + n];
        int v1 = histbuf[(size_t)(b + 1) * N_NODES + n];
        int v2 = histbuf[(size_t)(b + 2) * N_NODES + n];
        int v3 = histbuf[(size_t)(b + 3) * N_NODES + n];
        int v4 = histbuf[(size_t)(b + 4) * N_NODES + n];
        int v5 = histbuf[(size_t)(b + 5) * N_NODES + n];
        int v6 = histbuf[(size_t)(b + 6) * N_NODES + n];
        int v7 = histbuf[(size_t)(b + 7) * N_NODES + n];
        histbuf[(size_t)(b + 0) * N_NODES + n] = (unsigned short)run; run += v0;
        histbuf[(size_t)(b + 1) * N_NODES + n] = (unsigned short)run; run += v1;
        histbuf[(size_t)(b + 2) * N_NODES + n] = (unsigned short)run; run += v2;
        histbuf[(size_t)(b + 3) * N_NODES + n] = (unsigned short)run; run += v3;
        histbuf[(size_t)(b + 4) * N_NODES + n] = (unsigned short)run; run += v4;
        histbuf[(size_t)(b + 5) * N_NODES + n] = (unsigned short)run; run += v5;
        histbuf[(size_t)(b + 6) * N_NODES + n] = (unsigned short)run; run += v6;
        histbuf[(size_t)(b + 7) * N_NODES + n] = (unsigned short)run; run += v7;
    }
    cnt[n] = run + 1;   // +1: self-loop
}

// Pass 3: single-block scan of (cnt-1) -> rowptr; isd = rsqrt(cnt).
__global__ __launch_bounds__(256) void scan_kernel(const int* __restrict__ cnt,
                                                   int* __restrict__ rowptr,
                                                   float* __restrict__ isd) {
    __shared__ int scnt[10240];
    __shared__ int part[256];
    const int CH = 40;
    int t = threadIdx.x;
    for (int i = t; i < 2500; i += 256) ((int4*)scnt)[i] = ((const int4*)cnt)[i];  // 10000 ints
    for (int i = 10000 + t; i < 10240; i += 256) scnt[i] = 1;
    __syncthreads();
    int base = t * CH;
    int s = 0;
#pragma unroll 8
    for (int i = 0; i < CH; ++i) s += scnt[base + i] - 1;
    part[t] = s;
    __syncthreads();
    for (int off = 1; off < 256; off <<= 1) {
        int v = (t >= off) ? part[t - off] : 0;
        __syncthreads();
        part[t] += v;
        __syncthreads();
    }
    int run = (t == 0) ? 0 : part[t - 1];
    for (int i = 0; i < CH; ++i) {
        int idx = base + i;
        if (idx < N_NODES) {
            rowptr[idx] = run;
            int c = scnt[idx];
            run += c - 1;
            isd[idx] = rsqrtf((float)c);
        }
    }
    if (t == 255) rowptr[N_NODES] = run;
}

// Pass 4: pure-stream scatter; position = rowptr + block prefix + saved rank.
__global__ __launch_bounds__(256) void scatter_kernel(const int* __restrict__ src,
                                                      const int* __restrict__ dst,
                                                      const unsigned short* __restrict__ rank,
                                                      const int* __restrict__ rowptr,
                                                      const unsigned short* __restrict__ histbuf,
                                                      const float* __restrict__ isd,
                                                      int2* __restrict__ edat) {
    int e = blockIdx.x * 256 + threadIdx.x;
    if (e >= N_EDGES) return;
    int b = e / EPB;
    int s = src[e], d = dst[e];
    int pos = rowptr[d] + (int)histbuf[(size_t)b * N_NODES + d] + (int)rank[e];
    edat[pos] = make_int2(s, __float_as_int(isd[s] * isd[d]));
}

// W[k][n] f32 -> Wt_hi/lo[n][k] fp16 (transposed so mm's b-frag is contiguous).
// fp16 hi + fp16 lo covers ~22 mantissa bits of W.
__global__ __launch_bounds__(256) void wsplit_kernel(const float* __restrict__ W1,
                                                     const float* __restrict__ W2,
                                                     const float* __restrict__ W3,
                                                     unsigned short* __restrict__ wth,
                                                     unsigned short* __restrict__ wtl) {
    __shared__ float t[32][33];
    int b = blockIdx.x;                 // 3*64 blocks
    int w = b >> 6, tile = b & 63;
    int kt = (tile >> 3) << 5, nt = (tile & 7) << 5;
    const float* W = (w == 0) ? W1 : (w == 1) ? W2 : W3;
    int tid = threadIdx.x, r = tid >> 5, c = tid & 31;
#pragma unroll
    for (int i = 0; i < 4; ++i)
        t[r + 8 * i][c] = W[(size_t)(kt + r + 8 * i) * D + nt + c];
    __syncthreads();
    unsigned short* oh = wth + w * D * D;
    unsigned short* ol = wtl + w * D * D;
#pragma unroll
    for (int i = 0; i < 4; ++i) {
        float v = t[c][r + 8 * i];      // = W[kt+c][nt+r+8i]
        unsigned short hv = f2h(v);
        oh[(size_t)(nt + r + 8 * i) * D + kt + c] = hv;
        ol[(size_t)(nt + r + 8 * i) * D + kt + c] = f2h(v - h2f(hv));
    }
}

// ---------------- MFMA matmul: C_fp16[N,256] = A_fp16 @ (Wh+Wl) ----------------
// A is a single fp16 operand (exact for layers 2-3; one rounding for x in L1).
// 64x64 tile, BK=32, 4 waves 2x2, wave-tile 32x32, 8 MFMA/step.
template <int F32IN>
__global__ __launch_bounds__(256) void mm_kernel(const void* __restrict__ Av,
                                                 const unsigned short* __restrict__ Wh,
                                                 const unsigned short* __restrict__ Wl,
                                                 unsigned short* __restrict__ C) {
    __shared__ unsigned short sA[64][40], sWh[64][40], sWl[64][40];
    int tid = threadIdx.x;
    int lane = tid & 63, wid = tid >> 6;
    int wr = wid >> 1, wc = wid & 1;
    int row0 = blockIdx.x << 6;
    int n0 = blockIdx.y << 6;

    int sr = tid >> 2;              // 0..63 tile row
    int sk = (tid & 3) << 3;        // 0,8,16,24 k elems
    int arow = row0 + sr; if (arow >= N_NODES) arow = N_NODES - 1;  // clamp; stores guarded
    const float*          pAf = (const float*)Av + (size_t)arow * D + sk;
    const unsigned short* pAh = (const unsigned short*)Av + (size_t)arow * D + sk;
    const unsigned short* pWh = Wh + (size_t)(n0 + sr) * D + sk;
    const unsigned short* pWl = Wl + (size_t)(n0 + sr) * D + sk;

    float4 rf0, rf1; uint4 rAh;
    if (F32IN) { rf0 = *(const float4*)pAf; rf1 = *(const float4*)(pAf + 4); }
    else       { rAh = *(const uint4*)pAh; }
    uint4 rWh = *(const uint4*)pWh;
    uint4 rWl = *(const uint4*)pWl;

    int fr = lane & 15;
    int fk = (lane >> 4) << 3;

    floatx4 acc00 = {0.f, 0.f, 0.f, 0.f};
    floatx4 acc01 = acc00, acc10 = acc00, acc11 = acc00;

#pragma unroll 1
    for (int step = 0; step < D / 32; ++step) {
        if (F32IN) {   // in-register f32 -> fp16 convert, then stage
            float vv[8] = {rf0.x, rf0.y, rf0.z, rf0.w, rf1.x, rf1.y, rf1.z, rf1.w};
            union { unsigned short u[8]; uint4 v; } ph;
#pragma unroll
            for (int j = 0; j < 8; ++j) ph.u[j] = f2h(vv[j]);
            *(uint4*)&sA[sr][sk] = ph.v;
        } else {
            *(uint4*)&sA[sr][sk] = rAh;
        }
        *(uint4*)&sWh[sr][sk] = rWh;
        *(uint4*)&sWl[sr][sk] = rWl;
        __syncthreads();
        if (step < D / 32 - 1) {    // prefetch next k-slice
            if (F32IN) {
                rf0 = *(const float4*)(pAf + (step + 1) * 32);
                rf1 = *(const float4*)(pAf + (step + 1) * 32 + 4);
            } else {
                rAh = *(const uint4*)(pAh + (step + 1) * 32);
            }
            rWh = *(const uint4*)(pWh + (step + 1) * 32);
            rWl = *(const uint4*)(pWl + (step + 1) * 32);
        }
        half8 a0  = *(const half8*)&sA[(wr << 5) + fr][fk];
        half8 a1  = *(const half8*)&sA[(wr << 5) + 16 + fr][fk];
        half8 bh0 = *(const half8*)&sWh[(wc << 5) + fr][fk];
        half8 bh1 = *(const half8*)&sWh[(wc << 5) + 16 + fr][fk];
        half8 bl0 = *(const half8*)&sWl[(wc << 5) + fr][fk];
        half8 bl1 = *(const half8*)&sWl[(wc << 5) + 16 + fr][fk];
        acc00 = __builtin_amdgcn_mfma_f32_16x16x32_f16(a0, bh0, acc00, 0, 0, 0);
        acc00 = __builtin_amdgcn_mfma_f32_16x16x32_f16(a0, bl0, acc00, 0, 0, 0);
        acc01 = __builtin_amdgcn_mfma_f32_16x16x32_f16(a0, bh1, acc01, 0, 0, 0);
        acc01 = __builtin_amdgcn_mfma_f32_16x16x32_f16(a0, bl1, acc01, 0, 0, 0);
        acc10 = __builtin_amdgcn_mfma_f32_16x16x32_f16(a1, bh0, acc10, 0, 0, 0);
        acc10 = __builtin_amdgcn_mfma_f32_16x16x32_f16(a1, bl0, acc10, 0, 0, 0);
        acc11 = __builtin_amdgcn_mfma_f32_16x16x32_f16(a1, bh1, acc11, 0, 0, 0);
        acc11 = __builtin_amdgcn_mfma_f32_16x16x32_f16(a1, bl1, acc11, 0, 0, 0);
        __syncthreads();
    }

    // C/D layout: col = lane&15, row = (lane>>4)*4 + reg   [m89-verified]
    int crow = (lane >> 4) << 2;
    int colbase = n0 + (wc << 5) + fr;
#pragma unroll
    for (int r = 0; r < 4; ++r) {
        int gr0 = row0 + (wr << 5) + crow + r;
        if (gr0 < N_NODES) {
            C[(size_t)gr0 * D + colbase]      = f2h(acc00[r]);
            C[(size_t)gr0 * D + colbase + 16] = f2h(acc01[r]);
        }
        int gr1 = gr0 + 16;
        if (gr1 < N_NODES) {
            C[(size_t)gr1 * D + colbase]      = f2h(acc10[r]);
            C[(size_t)gr1 * D + colbase + 16] = f2h(acc11[r]);
        }
    }
}

// ---------------- aggregation: 1 node/block, 4 waves split the edge list --------
// h rows fp16 (512 B gathers); accumulate f32; output fp16.
__global__ __launch_bounds__(256) void agg_kernel(const unsigned short* __restrict__ h,
                                                  const int* __restrict__ rowptr,
                                                  const int2* __restrict__ edat,
                                                  const float* __restrict__ isd,
                                                  const float* __restrict__ bias,
                                                  unsigned short* __restrict__ outh) {
    __shared__ float part[4][D];
    int node = blockIdx.x;
    int tid = threadIdx.x;
    int w = tid >> 6, lane = tid & 63;
    int e0 = rowptr[node], e1 = rowptr[node + 1];
    int deg = e1 - e0;
    float4 acc = make_float4(0.f, 0.f, 0.f, 0.f);
    if (w == 0) {   // self-loop term
        float isd_i = isd[node];
        float selfn = isd_i * isd_i;
        ushort4 q = reinterpret_cast<const ushort4*>(h + (size_t)node * D)[lane];
        acc = make_float4(h2f(q.x) * selfn, h2f(q.y) * selfn,
                          h2f(q.z) * selfn, h2f(q.w) * selfn);
    }
    int c = (deg + 3) >> 2;
    int js = w * c;
    int je = min(js + c, deg);
    for (int base = js; base < je; base += 64) {
        int n = je - base; if (n > 64) n = 64;
        int2 ed = edat[e0 + base + ((lane < n) ? lane : 0)];
        int j = 0;
        for (; j + 8 <= n; j += 8) {
            int s0 = __shfl(ed.x, j + 0); float w0 = __int_as_float(__shfl(ed.y, j + 0));
            int s1 = __shfl(ed.x, j + 1); float w1 = __int_as_float(__shfl(ed.y, j + 1));
            int s2 = __shfl(ed.x, j + 2); float w2 = __int_as_float(__shfl(ed.y, j + 2));
            int s3 = __shfl(ed.x, j + 3); float w3 = __int_as_float(__shfl(ed.y, j + 3));
            int s4 = __shfl(ed.x, j + 4); float w4 = __int_as_float(__shfl(ed.y, j + 4));
            int s5 = __shfl(ed.x, j + 5); float w5 = __int_as_float(__shfl(ed.y, j + 5));
            int s6 = __shfl(ed.x, j + 6); float w6 = __int_as_float(__shfl(ed.y, j + 6));
            int s7 = __shfl(ed.x, j + 7); float w7 = __int_as_float(__shfl(ed.y, j + 7));
            ushort4 q0 = reinterpret_cast<const ushort4*>(h + (size_t)s0 * D)[lane];
            ushort4 q1 = reinterpret_cast<const ushort4*>(h + (size_t)s1 * D)[lane];
            ushort4 q2 = reinterpret_cast<const ushort4*>(h + (size_t)s2 * D)[lane];
            ushort4 q3 = reinterpret_cast<const ushort4*>(h + (size_t)s3 * D)[lane];
            ushort4 q4 = reinterpret_cast<const ushort4*>(h + (size_t)s4 * D)[lane];
            ushort4 q5 = reinterpret_cast<const ushort4*>(h + (size_t)s5 * D)[lane];
            ushort4 q6 = reinterpret_cast<const ushort4*>(h + (size_t)s6 * D)[lane];
            ushort4 q7 = reinterpret_cast<const ushort4*>(h + (size_t)s7 * D)[lane];
            acc.x = fmaf(h2f(q0.x), w0, acc.x); acc.y = fmaf(h2f(q0.y), w0, acc.y);
            acc.z = fmaf(h2f(q0.z), w0, acc.z); acc.w = fmaf(h2f(q0.w), w0, acc.w);
            acc.x = fmaf(h2f(q1.x), w1, acc.x); acc.y = fmaf(h2f(q1.y), w1, acc.y);
            acc.z = fmaf(h2f(q1.z), w1, acc.z); acc.w = fmaf(h2f(q1.w), w1, acc.w);
            acc.x = fmaf(h2f(q2.x), w2, acc.x); acc.y = fmaf(h2f(q2.y), w2, acc.y);
            acc.z = fmaf(h2f(q2.z), w2, acc.z); acc.w = fmaf(h2f(q2.w), w2, acc.w);
            acc.x = fmaf(h2f(q3.x), w3, acc.x); acc.y = fmaf(h2f(q3.y), w3, acc.y);
            acc.z = fmaf(h2f(q3.z), w3, acc.z); acc.w = fmaf(h2f(q3.w), w3, acc.w);
            acc.x = fmaf(h2f(q4.x), w4, acc.x); acc.y = fmaf(h2f(q4.y), w4, acc.y);
            acc.z = fmaf(h2f(q4.z), w4, acc.z); acc.w = fmaf(h2f(q4.w), w4, acc.w);
            acc.x = fmaf(h2f(q5.x), w5, acc.x); acc.y = fmaf(h2f(q5.y), w5, acc.y);
            acc.z = fmaf(h2f(q5.z), w5, acc.z); acc.w = fmaf(h2f(q5.w), w5, acc.w);
            acc.x = fmaf(h2f(q6.x), w6, acc.x); acc.y = fmaf(h2f(q6.y), w6, acc.y);
            acc.z = fmaf(h2f(q6.z), w6, acc.z); acc.w = fmaf(h2f(q6.w), w6, acc.w);
            acc.x = fmaf(h2f(q7.x), w7, acc.x); acc.y = fmaf(h2f(q7.y), w7, acc.y);
            acc.z = fmaf(h2f(q7.z), w7, acc.z); acc.w = fmaf(h2f(q7.w), w7, acc.w);
        }
        for (; j < n; ++j) {
            int s = __shfl(ed.x, j);
            float wt = __int_as_float(__shfl(ed.y, j));
            ushort4 q = reinterpret_cast<const ushort4*>(h + (size_t)s * D)[lane];
            acc.x = fmaf(h2f(q.x), wt, acc.x); acc.y = fmaf(h2f(q.y), wt, acc.y);
            acc.z = fmaf(h2f(q.z), wt, acc.z); acc.w = fmaf(h2f(q.w), wt, acc.w);
        }
    }
    reinterpret_cast<float4*>(part[w])[lane] = acc;
    __syncthreads();
    int t = tid;   // 256 threads = 256 dims
    float v = part[0][t] + part[1][t] + part[2][t] + part[3][t] + bias[t];
    outh[(size_t)node * D + t] = f2h(fmaxf(v, 0.f));
}

// ---------------- fused mean-pool + head (h fp16) ----------------
__global__ __launch_bounds__(256) void poolfinal_kernel(const unsigned short* __restrict__ h,
                                                        const int* __restrict__ batch,
                                                        const float* __restrict__ lw,
                                                        const float* __restrict__ lb,
                                                        float* __restrict__ out) {
    __shared__ float part[4][D];
    __shared__ float p[D];
    int g = blockIdx.x;
    int tid = threadIdx.x, w = tid >> 6, lane = tid & 63;
    int lo = 0, hi = N_NODES;
    while (lo < hi) { int m = (lo + hi) >> 1; if (batch[m] < g) lo = m + 1; else hi = m; }
    int start = lo;
    hi = N_NODES;
    while (lo < hi) { int m = (lo + hi) >> 1; if (batch[m] <= g) lo = m + 1; else hi = m; }
    int end = lo;
    float4 acc = make_float4(0.f, 0.f, 0.f, 0.f);
    for (int nd = start + w; nd < end; nd += 4) {
        ushort4 q = reinterpret_cast<const ushort4*>(h + (size_t)nd * D)[lane];
        acc.x += h2f(q.x); acc.y += h2f(q.y); acc.z += h2f(q.z); acc.w += h2f(q.w);
    }
    reinterpret_cast<float4*>(part[w])[lane] = acc;
    __syncthreads();
    float invc = 1.f / (float)((end > start) ? (end - start) : 1);
    p[tid] = (part[0][tid] + part[1][tid] + part[2][tid] + part[3][tid]) * invc;
    __syncthreads();
    if (tid < N_TASKS) {
        float a = lb[tid];
        for (int k = 0; k < D; ++k) a = fmaf(p[k], lw[k * N_TASKS + tid], a);
        out[g * N_TASKS + tid] = a;
    }
}

extern "C" void kernel_launch(void* const* d_in, const int* in_sizes, int n_in,
                              void* d_out, int out_size, void* d_ws, size_t ws_size,
                              hipStream_t stream) {
    const float* x   = (const float*)d_in[0];
    const int*   ei  = (const int*)d_in[1];
    const int*   bat = (const int*)d_in[2];
    const float* W1  = (const float*)d_in[3];
    const float* b1  = (const float*)d_in[4];
    const float* W2  = (const float*)d_in[5];
    const float* b2  = (const float*)d_in[6];
    const float* W3  = (const float*)d_in[7];
    const float* b3  = (const float*)d_in[8];
    const float* lw  = (const float*)d_in[9];
    const float* lb  = (const float*)d_in[10];
    float* out = (float*)d_out;

    const int* src = ei;
    const int* dst = ei + N_EDGES;

    char* ws = (char*)d_ws;
    unsigned short* gH      = (unsigned short*)(ws + 0);          //  5,120,000 (fp16 agg out)
    unsigned short* hH      = (unsigned short*)(ws + 5120000);    //  5,120,000 (fp16 mm out)
    unsigned short* Wth     = (unsigned short*)(ws + 10240000);   //    393,216
    unsigned short* Wtl     = (unsigned short*)(ws + 10633216);   //    393,216
    float*          isd     = (float*)         (ws + 11026432);   //     40,000
    int*            cnt     = (int*)           (ws + 11066432);   //     40,000
    int*            rowptr  = (int*)           (ws + 11106432);   //     40,016
    int2*           edat    = (int2*)          (ws + 11146448);   //  2,560,000
    unsigned short* histbuf = (unsigned short*)(ws + 13706448);   //  2,560,000
    unsigned short* rank    = (unsigned short*)(ws + 16266448);   //    640,000  (~17 MB)

    // CSR build (atomic-free) + weight split (once per call)
    histp_kernel<<<CSR_BLOCKS, 256, 0, stream>>>(dst, histbuf, rank);
    merge_kernel<<<(N_NODES + 255) / 256, 256, 0, stream>>>(histbuf, cnt);
    scan_kernel<<<1, 256, 0, stream>>>(cnt, rowptr, isd);
    scatter_kernel<<<(N_EDGES + 255) / 256, 256, 0, stream>>>(src, dst, rank, rowptr,
                                                              histbuf, isd, edat);
    wsplit_kernel<<<3 * 64, 256, 0, stream>>>(W1, W2, W3, Wth, Wtl);

    dim3 mmgrid((N_NODES + 63) / 64, D / 64);   // 157 x 4

    // Layer 1
    mm_kernel<1><<<mmgrid, 256, 0, stream>>>(x, Wth, Wtl, hH);
    agg_kernel<<<N_NODES, 256, 0, stream>>>(hH, rowptr, edat, isd, b1, gH);
    // Layer 2
    mm_kernel<0><<<mmgrid, 256, 0, stream>>>(gH, Wth + D * D, Wtl + D * D, hH);
    agg_kernel<<<N_NODES, 256, 0, stream>>>(hH, rowptr, edat, isd, b2, gH);
    // Layer 3
    mm_kernel<0><<<mmgrid, 256, 0, stream>>>(gH, Wth + 2 * D * D, Wtl + 2 * D * D, hH);
    agg_kernel<<<N_NODES, 256, 0, stream>>>(hH, rowptr, edat, isd, b3, gH);

    // Fused pool + head
    poolfinal_kernel<<<N_GRAPHS, 256, 0, stream>>>(gH, bat, lw, lb, out);
}

// Round 9
// 144.281 us; speedup vs baseline: 3.3936x; 1.1232x over previous
//
#include <hip/hip_runtime.h>

#define N_NODES  10000
#define N_EDGES  320000
#define D        256
#define N_TASKS  128
#define N_GRAPHS 128

#define CSR_BLOCKS 256
#define EPB (N_EDGES / CSR_BLOCKS)   // 1250 edges per block

typedef __attribute__((ext_vector_type(8))) _Float16 half8;
typedef __attribute__((ext_vector_type(4))) float floatx4;

__device__ __forceinline__ unsigned short f2h(float f) {
    _Float16 h = (_Float16)f;
    return *(unsigned short*)&h;
}
__device__ __forceinline__ float h2f(unsigned short u) {
    _Float16 h = *(_Float16*)&u;
    return (float)h;
}

// ---------------- CSR build, atomic-free (LDS-privatized counting sort) --------

__global__ __launch_bounds__(256) void histp_kernel(const int* __restrict__ dst,
                                                    unsigned short* __restrict__ histbuf,
                                                    unsigned short* __restrict__ rank) {
    __shared__ int h[N_NODES];   // 40 KB
    int b = blockIdx.x, t = threadIdx.x;
    for (int i = t; i < N_NODES; i += 256) h[i] = 0;
    __syncthreads();
    int e0 = b * EPB;
    for (int i = t; i < EPB; i += 256) {
        int e = e0 + i;
        int r = atomicAdd(&h[dst[e]], 1);
        rank[e] = (unsigned short)r;
    }
    __syncthreads();
    unsigned short* outp = histbuf + (size_t)b * N_NODES;
    for (int i = t; i < N_NODES; i += 256) outp[i] = (unsigned short)h[i];
}

__global__ __launch_bounds__(256) void merge_kernel(unsigned short* __restrict__ histbuf,
                                                    int* __restrict__ cnt) {
    int n = blockIdx.x * 256 + threadIdx.x;
    if (n >= N_NODES) return;
    int run = 0;
#pragma unroll 1
    for (int b = 0; b < CSR_BLOCKS; b += 8) {
        int v0 = histbuf[(size_t)(b + 0) * N_NODES + n];
        int v1 = histbuf[(size_t)(b + 1) * N_NODES + n];
        int v2 = histbuf[(size_t)(b + 2) * N_NODES + n];
        int v3 = histbuf[(size_t)(b + 3) * N_NODES + n];
        int v4 = histbuf[(size_t)(b + 4) * N_NODES + n];
        int v5 = histbuf[(size_t)(b + 5) * N_NODES + n];
        int v6 = histbuf[(size_t)(b + 6) * N_NODES + n];
        int v7 = histbuf[(size_t)(b + 7) * N_NODES + n];
        histbuf[(size_t)(b + 0) * N_NODES + n] = (unsigned short)run; run += v0;
        histbuf[(size_t)(b + 1) * N_NODES + n] = (unsigned short)run; run += v1;
        histbuf[(size_t)(b + 2) * N_NODES + n] = (unsigned short)run; run += v2;
        histbuf[(size_t)(b + 3) * N_NODES + n] = (unsigned short)run; run += v3;
        histbuf[(size_t)(b + 4) * N_NODES + n] = (unsigned short)run; run += v4;
        histbuf[(size_t)(b + 5) * N_NODES + n] = (unsigned short)run; run += v5;
        histbuf[(size_t)(b + 6) * N_NODES + n] = (unsigned short)run; run += v6;
        histbuf[(size_t)(b + 7) * N_NODES + n] = (unsigned short)run; run += v7;
    }
    cnt[n] = run + 1;   // +1: self-loop
}

__global__ __launch_bounds__(256) void scan_kernel(const int* __restrict__ cnt,
                                                   int* __restrict__ rowptr,
                                                   float* __restrict__ isd) {
    __shared__ int scnt[10240];
    __shared__ int part[256];
    const int CH = 40;
    int t = threadIdx.x;
    for (int i = t; i < 2500; i += 256) ((int4*)scnt)[i] = ((const int4*)cnt)[i];  // 10000 ints
    for (int i = 10000 + t; i < 10240; i += 256) scnt[i] = 1;
    __syncthreads();
    int base = t * CH;
    int s = 0;
#pragma unroll 8
    for (int i = 0; i < CH; ++i) s += scnt[base + i] - 1;
    part[t] = s;
    __syncthreads();
    for (int off = 1; off < 256; off <<= 1) {
        int v = (t >= off) ? part[t - off] : 0;
        __syncthreads();
        part[t] += v;
        __syncthreads();
    }
    int run = (t == 0) ? 0 : part[t - 1];
    for (int i = 0; i < CH; ++i) {
        int idx = base + i;
        if (idx < N_NODES) {
            rowptr[idx] = run;
            int c = scnt[idx];
            run += c - 1;
            isd[idx] = rsqrtf((float)c);
        }
    }
    if (t == 255) rowptr[N_NODES] = run;
}

__global__ __launch_bounds__(256) void scatter_kernel(const int* __restrict__ src,
                                                      const int* __restrict__ dst,
                                                      const unsigned short* __restrict__ rank,
                                                      const int* __restrict__ rowptr,
                                                      const unsigned short* __restrict__ histbuf,
                                                      const float* __restrict__ isd,
                                                      int2* __restrict__ edat) {
    int e = blockIdx.x * 256 + threadIdx.x;
    if (e >= N_EDGES) return;
    int b = e / EPB;
    int s = src[e], d = dst[e];
    int pos = rowptr[d] + (int)histbuf[(size_t)b * N_NODES + d] + (int)rank[e];
    edat[pos] = make_int2(s, __float_as_int(isd[s] * isd[d]));
}

// W[k][n] f32 -> Wt[n][k] fp16 (transposed; single plane — error analysis shows
// the lo-plane is below the fp16-h storage noise).
__global__ __launch_bounds__(256) void wsplit_kernel(const float* __restrict__ W1,
                                                     const float* __restrict__ W2,
                                                     const float* __restrict__ W3,
                                                     unsigned short* __restrict__ wt) {
    __shared__ float t[32][33];
    int b = blockIdx.x;                 // 3*64 blocks
    int w = b >> 6, tile = b & 63;
    int kt = (tile >> 3) << 5, nt = (tile & 7) << 5;
    const float* W = (w == 0) ? W1 : (w == 1) ? W2 : W3;
    int tid = threadIdx.x, r = tid >> 5, c = tid & 31;
#pragma unroll
    for (int i = 0; i < 4; ++i)
        t[r + 8 * i][c] = W[(size_t)(kt + r + 8 * i) * D + nt + c];
    __syncthreads();
    unsigned short* oh = wt + w * D * D;
#pragma unroll
    for (int i = 0; i < 4; ++i)
        oh[(size_t)(nt + r + 8 * i) * D + kt + c] = f2h(t[c][r + 8 * i]);
}

// ---------------- MFMA matmul: C_fp16[N,256] = A_fp16 @ W_fp16 -----------------
// 64x64 tile, BK=32, 4 waves 2x2, wave-tile 32x32, 4 MFMA/step.
template <int F32IN>
__global__ __launch_bounds__(256) void mm_kernel(const void* __restrict__ Av,
                                                 const unsigned short* __restrict__ Wt,
                                                 unsigned short* __restrict__ C) {
    __shared__ unsigned short sA[64][40], sW[64][40];
    int tid = threadIdx.x;
    int lane = tid & 63, wid = tid >> 6;
    int wr = wid >> 1, wc = wid & 1;
    int row0 = blockIdx.x << 6;
    int n0 = blockIdx.y << 6;

    int sr = tid >> 2;              // 0..63 tile row
    int sk = (tid & 3) << 3;        // 0,8,16,24 k elems
    int arow = row0 + sr; if (arow >= N_NODES) arow = N_NODES - 1;  // clamp; stores guarded
    const float*          pAf = (const float*)Av + (size_t)arow * D + sk;
    const unsigned short* pAh = (const unsigned short*)Av + (size_t)arow * D + sk;
    const unsigned short* pW  = Wt + (size_t)(n0 + sr) * D + sk;

    float4 rf0, rf1; uint4 rAh;
    if (F32IN) { rf0 = *(const float4*)pAf; rf1 = *(const float4*)(pAf + 4); }
    else       { rAh = *(const uint4*)pAh; }
    uint4 rW = *(const uint4*)pW;

    int fr = lane & 15;
    int fk = (lane >> 4) << 3;

    floatx4 acc00 = {0.f, 0.f, 0.f, 0.f};
    floatx4 acc01 = acc00, acc10 = acc00, acc11 = acc00;

#pragma unroll 1
    for (int step = 0; step < D / 32; ++step) {
        if (F32IN) {   // in-register f32 -> fp16 convert, then stage
            float vv[8] = {rf0.x, rf0.y, rf0.z, rf0.w, rf1.x, rf1.y, rf1.z, rf1.w};
            union { unsigned short u[8]; uint4 v; } ph;
#pragma unroll
            for (int j = 0; j < 8; ++j) ph.u[j] = f2h(vv[j]);
            *(uint4*)&sA[sr][sk] = ph.v;
        } else {
            *(uint4*)&sA[sr][sk] = rAh;
        }
        *(uint4*)&sW[sr][sk] = rW;
        __syncthreads();
        if (step < D / 32 - 1) {    // prefetch next k-slice
            if (F32IN) {
                rf0 = *(const float4*)(pAf + (step + 1) * 32);
                rf1 = *(const float4*)(pAf + (step + 1) * 32 + 4);
            } else {
                rAh = *(const uint4*)(pAh + (step + 1) * 32);
            }
            rW = *(const uint4*)(pW + (step + 1) * 32);
        }
        half8 a0 = *(const half8*)&sA[(wr << 5) + fr][fk];
        half8 a1 = *(const half8*)&sA[(wr << 5) + 16 + fr][fk];
        half8 b0 = *(const half8*)&sW[(wc << 5) + fr][fk];
        half8 b1 = *(const half8*)&sW[(wc << 5) + 16 + fr][fk];
        acc00 = __builtin_amdgcn_mfma_f32_16x16x32_f16(a0, b0, acc00, 0, 0, 0);
        acc01 = __builtin_amdgcn_mfma_f32_16x16x32_f16(a0, b1, acc01, 0, 0, 0);
        acc10 = __builtin_amdgcn_mfma_f32_16x16x32_f16(a1, b0, acc10, 0, 0, 0);
        acc11 = __builtin_amdgcn_mfma_f32_16x16x32_f16(a1, b1, acc11, 0, 0, 0);
        __syncthreads();
    }

    // C/D layout: col = lane&15, row = (lane>>4)*4 + reg   [m89-verified]
    int crow = (lane >> 4) << 2;
    int colbase = n0 + (wc << 5) + fr;
#pragma unroll
    for (int r = 0; r < 4; ++r) {
        int gr0 = row0 + (wr << 5) + crow + r;
        if (gr0 < N_NODES) {
            C[(size_t)gr0 * D + colbase]      = f2h(acc00[r]);
            C[(size_t)gr0 * D + colbase + 16] = f2h(acc01[r]);
        }
        int gr1 = gr0 + 16;
        if (gr1 < N_NODES) {
            C[(size_t)gr1 * D + colbase]      = f2h(acc10[r]);
            C[(size_t)gr1 * D + colbase + 16] = f2h(acc11[r]);
        }
    }
}

// ---------------- aggregation: 1 wave/node, 2 rows per dwordx4 load ------------
// Lanes 0-31 carry the even edge of each pair, lanes 32-63 the odd edge; each
// lane holds 8 dims (16 B). Half-wave fold via shfl_xor(32); no LDS, no barriers.
__device__ __forceinline__ void fma8(uint4 q, float wt, float* acc) {
    acc[0] = fmaf(h2f((unsigned short)(q.x & 0xffff)), wt, acc[0]);
    acc[1] = fmaf(h2f((unsigned short)(q.x >> 16)),    wt, acc[1]);
    acc[2] = fmaf(h2f((unsigned short)(q.y & 0xffff)), wt, acc[2]);
    acc[3] = fmaf(h2f((unsigned short)(q.y >> 16)),    wt, acc[3]);
    acc[4] = fmaf(h2f((unsigned short)(q.z & 0xffff)), wt, acc[4]);
    acc[5] = fmaf(h2f((unsigned short)(q.z >> 16)),    wt, acc[5]);
    acc[6] = fmaf(h2f((unsigned short)(q.w & 0xffff)), wt, acc[6]);
    acc[7] = fmaf(h2f((unsigned short)(q.w >> 16)),    wt, acc[7]);
}

__global__ __launch_bounds__(256) void agg_kernel(const unsigned short* __restrict__ h,
                                                  const int* __restrict__ rowptr,
                                                  const int2* __restrict__ edat,
                                                  const float* __restrict__ isd,
                                                  const float* __restrict__ bias,
                                                  unsigned short* __restrict__ outh) {
    int node = (blockIdx.x * blockDim.x + threadIdx.x) >> 6;
    if (node >= N_NODES) return;
    int lane = threadIdx.x & 63;
    int half = lane >> 5;            // 0: even edge of pair, 1: odd edge
    int sub  = lane & 31;            // dims sub*8 .. sub*8+7

    float acc[8] = {0.f, 0.f, 0.f, 0.f, 0.f, 0.f, 0.f, 0.f};

    // self-loop (half 0 carries it; half 1 contributes 0)
    float isd_i = isd[node];
    float selfw = half ? 0.f : isd_i * isd_i;
    uint4 qs = *(const uint4*)(h + (size_t)node * D + (sub << 3));
    fma8(qs, selfw, acc);

    int e0 = rowptr[node];
    int deg = rowptr[node + 1] - e0;
    for (int base = 0; base < deg; base += 64) {
        int n = deg - base; if (n > 64) n = 64;
        int2 ed = edat[e0 + base + ((lane < n) ? lane : 0)];
        int pairs = (n + 1) >> 1;
        for (int p0 = 0; p0 < pairs; p0 += 8) {
            uint4 q[8]; float wt[8];
#pragma unroll
            for (int u = 0; u < 8; ++u) {
                int idx = ((p0 + u) << 1) + half;
                int idc = (idx < n) ? idx : 0;
                int s = __shfl(ed.x, idc);
                wt[u] = (idx < n && (p0 + u) < pairs)
                            ? __int_as_float(__shfl(ed.y, idc)) : 0.f;
                q[u] = *(const uint4*)(h + (size_t)s * D + (sub << 3));
            }
#pragma unroll
            for (int u = 0; u < 8; ++u) fma8(q[u], wt[u], acc);
        }
    }

    // fold the two half-waves
#pragma unroll
    for (int i = 0; i < 8; ++i) acc[i] += __shfl_xor(acc[i], 32);

    if (half == 0) {
        const float* bp = bias + (sub << 3);
        float4 b0 = *(const float4*)bp;
        float4 b1 = *(const float4*)(bp + 4);
        float r0 = fmaxf(acc[0] + b0.x, 0.f), r1 = fmaxf(acc[1] + b0.y, 0.f);
        float r2 = fmaxf(acc[2] + b0.z, 0.f), r3 = fmaxf(acc[3] + b0.w, 0.f);
        float r4 = fmaxf(acc[4] + b1.x, 0.f), r5 = fmaxf(acc[5] + b1.y, 0.f);
        float r6 = fmaxf(acc[6] + b1.z, 0.f), r7 = fmaxf(acc[7] + b1.w, 0.f);
        uint4 o;
        o.x = (unsigned)f2h(r0) | ((unsigned)f2h(r1) << 16);
        o.y = (unsigned)f2h(r2) | ((unsigned)f2h(r3) << 16);
        o.z = (unsigned)f2h(r4) | ((unsigned)f2h(r5) << 16);
        o.w = (unsigned)f2h(r6) | ((unsigned)f2h(r7) << 16);
        *(uint4*)(outh + (size_t)node * D + (sub << 3)) = o;
    }
}

// ---------------- fused mean-pool + head (h fp16) ----------------
__global__ __launch_bounds__(256) void poolfinal_kernel(const unsigned short* __restrict__ h,
                                                        const int* __restrict__ batch,
                                                        const float* __restrict__ lw,
                                                        const float* __restrict__ lb,
                                                        float* __restrict__ out) {
    __shared__ float part[4][D];
    __shared__ float p[D];
    int g = blockIdx.x;
    int tid = threadIdx.x, w = tid >> 6, lane = tid & 63;
    int lo = 0, hi = N_NODES;
    while (lo < hi) { int m = (lo + hi) >> 1; if (batch[m] < g) lo = m + 1; else hi = m; }
    int start = lo;
    hi = N_NODES;
    while (lo < hi) { int m = (lo + hi) >> 1; if (batch[m] <= g) lo = m + 1; else hi = m; }
    int end = lo;
    float4 acc = make_float4(0.f, 0.f, 0.f, 0.f);
    for (int nd = start + w; nd < end; nd += 4) {
        ushort4 q = reinterpret_cast<const ushort4*>(h + (size_t)nd * D)[lane];
        acc.x += h2f(q.x); acc.y += h2f(q.y); acc.z += h2f(q.z); acc.w += h2f(q.w);
    }
    reinterpret_cast<float4*>(part[w])[lane] = acc;
    __syncthreads();
    float invc = 1.f / (float)((end > start) ? (end - start) : 1);
    p[tid] = (part[0][tid] + part[1][tid] + part[2][tid] + part[3][tid]) * invc;
    __syncthreads();
    if (tid < N_TASKS) {
        float a = lb[tid];
        for (int k = 0; k < D; ++k) a = fmaf(p[k], lw[k * N_TASKS + tid], a);
        out[g * N_TASKS + tid] = a;
    }
}

extern "C" void kernel_launch(void* const* d_in, const int* in_sizes, int n_in,
                              void* d_out, int out_size, void* d_ws, size_t ws_size,
                              hipStream_t stream) {
    const float* x   = (const float*)d_in[0];
    const int*   ei  = (const int*)d_in[1];
    const int*   bat = (const int*)d_in[2];
    const float* W1  = (const float*)d_in[3];
    const float* b1  = (const float*)d_in[4];
    const float* W2  = (const float*)d_in[5];
    const float* b2  = (const float*)d_in[6];
    const float* W3  = (const float*)d_in[7];
    const float* b3  = (const float*)d_in[8];
    const float* lw  = (const float*)d_in[9];
    const float* lb  = (const float*)d_in[10];
    float* out = (float*)d_out;

    const int* src = ei;
    const int* dst = ei + N_EDGES;

    char* ws = (char*)d_ws;
    unsigned short* gH      = (unsigned short*)(ws + 0);          //  5,120,000 (fp16 agg out)
    unsigned short* hH      = (unsigned short*)(ws + 5120000);    //  5,120,000 (fp16 mm out)
    unsigned short* Wt      = (unsigned short*)(ws + 10240000);   //    393,216
    float*          isd     = (float*)         (ws + 10633216);   //     40,000
    int*            cnt     = (int*)           (ws + 10673216);   //     40,000
    int*            rowptr  = (int*)           (ws + 10713216);   //     40,016
    int2*           edat    = (int2*)          (ws + 10753232);   //  2,560,000
    unsigned short* histbuf = (unsigned short*)(ws + 13313232);   //  5,120,000
    unsigned short* rank    = (unsigned short*)(ws + 18433232);   //    640,000  (~19 MB)

    // CSR build (atomic-free) + weight split (once per call)
    histp_kernel<<<CSR_BLOCKS, 256, 0, stream>>>(dst, histbuf, rank);
    merge_kernel<<<(N_NODES + 255) / 256, 256, 0, stream>>>(histbuf, cnt);
    scan_kernel<<<1, 256, 0, stream>>>(cnt, rowptr, isd);
    scatter_kernel<<<(N_EDGES + 255) / 256, 256, 0, stream>>>(src, dst, rank, rowptr,
                                                              histbuf, isd, edat);
    wsplit_kernel<<<3 * 64, 256, 0, stream>>>(W1, W2, W3, Wt);

    dim3 mmgrid((N_NODES + 63) / 64, D / 64);   // 157 x 4
    const int AGG_BLOCKS = N_NODES / 4;         // 2500 (1 wave per node)

    // Layer 1
    mm_kernel<1><<<mmgrid, 256, 0, stream>>>(x, Wt, hH);
    agg_kernel<<<AGG_BLOCKS, 256, 0, stream>>>(hH, rowptr, edat, isd, b1, gH);
    // Layer 2
    mm_kernel<0><<<mmgrid, 256, 0, stream>>>(gH, Wt + D * D, hH);
    agg_kernel<<<AGG_BLOCKS, 256, 0, stream>>>(hH, rowptr, edat, isd, b2, gH);
    // Layer 3
    mm_kernel<0><<<mmgrid, 256, 0, stream>>>(gH, Wt + 2 * D * D, hH);
    agg_kernel<<<AGG_BLOCKS, 256, 0, stream>>>(hH, rowptr, edat, isd, b3, gH);

    // Fused pool + head
    poolfinal_kernel<<<N_GRAPHS, 256, 0, stream>>>(gH, bat, lw, lb, out);
}